// Round 3
// baseline (549.504 us; speedup 1.0000x reference)
//
#include <hip/hip_runtime.h>

#define NB 64
#define NN 1024
#define WDIM 64
#define RR 4
#define HID 512
#define XID 471
#define EPSF 1e-6f

// ---- d_out offsets (floats) ----
#define O_OUT   0
#define O_XI    16384
#define O_RW    46528
#define O_MEM   308672
#define O_USAGE 4502976

// ---- ws offsets (floats) ----
#define WS_RFPART   0          // [4][64][256] read_flat partials
#define WS_H        65536      // [64][512]
#define WS_IFACE    98304      // [64][480]
#define WS_ALLOC    129024     // [64][1024]
#define WS_WW       194560     // [64][1024]
#define WS_V        260096     // [64][1024][8]
#define WS_ST       784384     // [64][8]
#define WS_DIAG     784896     // [64][1024]
#define WS_ROWAB    850432     // [64][1024][8]
#define WS_COLPART  1899008    // [8][64][1024][8] col partials (16.8 MB)

// ---- iface per-b layout (stride 480) ----
#define IF_KN     0
#define IF_WKN    256
#define IF_ERASE  320
#define IF_WVEC   384
#define IF_RSTR   448
#define IF_FREE   452
#define IF_WSTR   456
#define IF_AG     457
#define IF_WG     458
#define IF_MODES  460
#define IF_STRIDE 480

__device__ __forceinline__ float sigmoidf_(float x) { return 1.0f / (1.0f + expf(-x)); }
__device__ __forceinline__ float oneplusf_(float x) {
  return 1.0f + ((x > 20.0f) ? x : log1pf(expf(x)));
}

// block reductions for 16-wave (1024-thread) blocks
__device__ __forceinline__ float blockSum16(float v, float* red) {
  #pragma unroll
  for (int s = 32; s; s >>= 1) v += __shfl_xor(v, s);
  __syncthreads();
  if ((threadIdx.x & 63) == 0) red[threadIdx.x >> 6] = v;
  __syncthreads();
  float s = 0.0f;
  #pragma unroll
  for (int i = 0; i < 16; ++i) s += red[i];
  return s;
}
__device__ __forceinline__ float blockMax16(float v, float* red) {
  #pragma unroll
  for (int s = 32; s; s >>= 1) v = fmaxf(v, __shfl_xor(v, s));
  __syncthreads();
  if ((threadIdx.x & 63) == 0) red[threadIdx.x >> 6] = v;
  __syncthreads();
  float m = red[0];
  #pragma unroll
  for (int i = 1; i < 16; ++i) m = fmaxf(m, red[i]);
  return m;
}

// 1) read_flat partials: part[q][b][r*64+w] = sum_{n in q-range} M[b,n,w]*rw[b,n,r]
__global__ __launch_bounds__(1024) void k_read_flat(const float* __restrict__ mem,
                                                    const float* __restrict__ rw,
                                                    float* __restrict__ ws) {
  __shared__ float red[1024];
  const int q = blockIdx.x, b = blockIdx.y, t = threadIdx.x;
  const int rwi = t & 255;
  const int r = rwi >> 6, w = rwi & 63;
  const int ng = t >> 8;
  const int n0 = (q << 8) + (ng << 6);
  const float* M  = mem + ((size_t)(b << 10) + n0) * WDIM;
  const float* Rw = rw  + ((size_t)(b << 10) + n0) * RR;
  float a0 = 0.f, a1 = 0.f, a2 = 0.f, a3 = 0.f;
  for (int n = 0; n < 64; n += 4) {
    a0 += M[(n + 0) * WDIM + w] * Rw[(n + 0) * RR + r];
    a1 += M[(n + 1) * WDIM + w] * Rw[(n + 1) * RR + r];
    a2 += M[(n + 2) * WDIM + w] * Rw[(n + 2) * RR + r];
    a3 += M[(n + 3) * WDIM + w] * Rw[(n + 3) * RR + r];
  }
  red[t] = (a0 + a1) + (a2 + a3);
  __syncthreads();
  if (t < 256)
    ws[WS_RFPART + (((q << 6) + b) << 8) + t] =
        red[t] + red[t + 256] + red[t + 512] + red[t + 768];
}

// 2) h = relu([x, read_flat] @ W1 + b1)   (sums the 4 read_flat partials)
__global__ __launch_bounds__(512) void k_h(const float* __restrict__ x,
                                           const float* __restrict__ W1,
                                           const float* __restrict__ b1,
                                           float* __restrict__ ws) {
  __shared__ float cat[768];
  const int b = blockIdx.x, t = threadIdx.x;
  cat[t] = x[b * 512 + t];
  if (t < 256) {
    float s = 0.0f;
    #pragma unroll
    for (int q = 0; q < 4; ++q) s += ws[WS_RFPART + (((q << 6) + b) << 8) + t];
    cat[512 + t] = s;
  }
  __syncthreads();
  float acc = b1[t];
  #pragma unroll 2
  for (int k = 0; k < 768; k += 4) {
    acc += cat[k] * W1[k * 512 + t];
    acc += cat[k + 1] * W1[(k + 1) * 512 + t];
    acc += cat[k + 2] * W1[(k + 2) * 512 + t];
    acc += cat[k + 3] * W1[(k + 3) * 512 + t];
  }
  ws[WS_H + b * 512 + t] = fmaxf(acc, 0.0f);
}

// 3) output = h@Wo + bo + read_flat@Wr + br
__global__ __launch_bounds__(256) void k_out(const float* __restrict__ Wo,
                                             const float* __restrict__ bo,
                                             const float* __restrict__ Wr,
                                             const float* __restrict__ br,
                                             const float* __restrict__ ws,
                                             float* __restrict__ out) {
  __shared__ float h[512];
  __shared__ float rf[256];
  const int b = blockIdx.x, t = threadIdx.x;
  h[t] = ws[WS_H + b * 512 + t];
  h[256 + t] = ws[WS_H + b * 512 + 256 + t];
  {
    float s = 0.0f;
    #pragma unroll
    for (int q = 0; q < 4; ++q) s += ws[WS_RFPART + (((q << 6) + b) << 8) + t];
    rf[t] = s;
  }
  __syncthreads();
  float acc = bo[t] + br[t];
  #pragma unroll 4
  for (int j = 0; j < 512; ++j) acc += h[j] * Wo[j * 256 + t];
  #pragma unroll 4
  for (int j = 0; j < 256; ++j) acc += rf[j] * Wr[j * 256 + t];
  out[O_OUT + b * 256 + t] = acc;
}

// 4) xi = h@Wxi + bxi, then interface activations (fused, wave 0)
__global__ __launch_bounds__(512) void k_xi(const float* __restrict__ Wxi,
                                            const float* __restrict__ bxi,
                                            float* __restrict__ ws,
                                            float* __restrict__ out) {
  __shared__ float h[512];
  __shared__ float xs[XID];
  const int b = blockIdx.x, t = threadIdx.x;
  h[t] = ws[WS_H + b * 512 + t];
  __syncthreads();
  if (t < XID) {
    float acc = bxi[t];
    #pragma unroll 4
    for (int j = 0; j < 512; ++j) acc += h[j] * Wxi[j * XID + t];
    out[O_XI + b * XID + t] = acc;
    xs[t] = acc;
  }
  __syncthreads();
  if (t < 64) {
    const int w = t;
    float* f = ws + WS_IFACE + (size_t)b * IF_STRIDE;
    #pragma unroll
    for (int r = 0; r < 4; ++r) {
      float kv = xs[r * 64 + w];
      float ss = kv * kv;
      #pragma unroll
      for (int s = 32; s; s >>= 1) ss += __shfl_xor(ss, s);
      f[IF_KN + r * 64 + w] = kv * rsqrtf(ss + EPSF);
    }
    {
      float kv = xs[260 + w];
      float ss = kv * kv;
      #pragma unroll
      for (int s = 32; s; s >>= 1) ss += __shfl_xor(ss, s);
      f[IF_WKN + w] = kv * rsqrtf(ss + EPSF);
    }
    f[IF_ERASE + w] = sigmoidf_(xs[325 + w]);
    f[IF_WVEC + w] = xs[389 + w];
    if (w < 4) {
      f[IF_RSTR + w] = oneplusf_(xs[256 + w]);
      f[IF_FREE + w] = sigmoidf_(xs[453 + w]);
      float a = xs[459 + w * 3], bb = xs[459 + w * 3 + 1], c = xs[459 + w * 3 + 2];
      float m = fmaxf(a, fmaxf(bb, c));
      float ea = expf(a - m), eb = expf(bb - m), ec = expf(c - m);
      float s = ea + eb + ec;
      f[IF_MODES + w * 3] = ea / s;
      f[IF_MODES + w * 3 + 1] = eb / s;
      f[IF_MODES + w * 3 + 2] = ec / s;
    }
    if (w == 0) {
      f[IF_WSTR] = oneplusf_(xs[324]);
      f[IF_AG] = sigmoidf_(xs[457]);
      f[IF_WG] = sigmoidf_(xs[458]);
    }
  }
}

// 5) usage_new (fused) + allocation: bitonic sort + product scan + scatter
__global__ __launch_bounds__(512) void k_alloc(const float* __restrict__ rw,
                                               const float* __restrict__ usage,
                                               const float* __restrict__ wwp,
                                               float* __restrict__ ws,
                                               float* __restrict__ ousage) {
  __shared__ float us[1024];
  __shared__ int idx[1024];
  __shared__ float cp[2][1024];
  const int b = blockIdx.x, t = threadIdx.x;
  const float* fr = ws + WS_IFACE + (size_t)b * IF_STRIDE + IF_FREE;
  const float f0 = fr[0], f1 = fr[1], f2 = fr[2], f3 = fr[3];
  #pragma unroll
  for (int hh = 0; hh < 2; ++hh) {
    const int n = t + (hh << 9);
    const int i = (b << 10) + n;
    const float4 r4 = *(const float4*)(rw + (size_t)i * 4);
    float ret = (1.0f - f0 * r4.x) * (1.0f - f1 * r4.y) *
                (1.0f - f2 * r4.z) * (1.0f - f3 * r4.w);
    float u = usage[i], w = wwp[i];
    float un = (u + w - u * w) * ret;
    ousage[i] = un;
    us[n] = un;
    idx[n] = n;
  }
  __syncthreads();
  for (int k = 2; k <= 1024; k <<= 1) {
    for (int j = k >> 1; j > 0; j >>= 1) {
      int i = ((t & ~(j - 1)) << 1) | (t & (j - 1));
      int ix = i | j;
      bool up = ((i & k) == 0);
      float a = us[i], c = us[ix];
      int ia = idx[i], ic = idx[ix];
      bool gt = (a > c) || (a == c && ia > ic);
      if (gt == up) { us[i] = c; us[ix] = a; idx[i] = ic; idx[ix] = ia; }
      __syncthreads();
    }
  }
  cp[0][t] = us[t];
  cp[0][t + 512] = us[t + 512];
  __syncthreads();
  int src = 0;
  for (int off = 1; off < 1024; off <<= 1) {
    int dst = src ^ 1;
    for (int e = t; e < 1024; e += 512)
      cp[dst][e] = (e >= off) ? cp[src][e] * cp[src][e - off] : cp[src][e];
    __syncthreads();
    src = dst;
  }
  for (int e = t; e < 1024; e += 512) {
    float cpe = (e == 0) ? 1.0f : cp[src][e - 1];
    ws[WS_ALLOC + (b << 10) + idx[e]] = (1.0f - us[e]) * cpe;
  }
}

// 6) write-content softmax + ww + v-vectors + S/T + link diagonal
__global__ __launch_bounds__(1024) void k_wcww(const float* __restrict__ mem,
                                               const float* __restrict__ rw,
                                               const float* __restrict__ prec,
                                               const float* __restrict__ link,
                                               float* __restrict__ ws) {
  __shared__ float wkn[64];
  __shared__ float red[16];
  const int b = blockIdx.x, t = threadIdx.x;
  const float* f = ws + WS_IFACE + (size_t)b * IF_STRIDE;
  if (t < 64) wkn[t] = f[IF_WKN + t];
  __syncthreads();
  const float* Mrow = mem + ((size_t)(b << 10) + t) * WDIM;
  float dot = 0.0f, ssq = 0.0f;
  #pragma unroll
  for (int w = 0; w < 64; w += 4) {
    float4 m4 = *(const float4*)(Mrow + w);
    float4 k4 = *(const float4*)(&wkn[w]);
    dot += m4.x * k4.x + m4.y * k4.y + m4.z * k4.z + m4.w * k4.w;
    ssq += m4.x * m4.x + m4.y * m4.y + m4.z * m4.z + m4.w * m4.w;
  }
  float sim = dot * rsqrtf(ssq + EPSF) * f[IF_WSTR];
  float bmax = blockMax16(sim, red);
  float e = expf(sim - bmax);
  float bsum = blockSum16(e, red);
  float wc = e / bsum;
  float ag = f[IF_AG], wg = f[IF_WG];
  float ww = wg * (ag * ws[WS_ALLOC + (b << 10) + t] + (1.0f - ag) * wc);
  ws[WS_WW + (b << 10) + t] = ww;
  float4 r4 = *(const float4*)(rw + ((size_t)(b << 10) + t) * 4);
  float* vp = ws + WS_V + ((size_t)(b << 10) + t) * 8;
  vp[0] = r4.x; vp[1] = r4.y; vp[2] = r4.z; vp[3] = r4.w;
  vp[4] = ww * r4.x; vp[5] = ww * r4.y; vp[6] = ww * r4.z; vp[7] = ww * r4.w;
  ws[WS_DIAG + (b << 10) + t] = link[((size_t)(b << 10) + t) * 1024 + t];
  float p = prec[(b << 10) + t];
  float rv[4] = {r4.x, r4.y, r4.z, r4.w};
  #pragma unroll
  for (int r = 0; r < 4; ++r) {
    float s = blockSum16(p * rv[r], red);
    if (t == 0) ws[WS_ST + b * 8 + r] = s;
  }
  #pragma unroll
  for (int r = 0; r < 4; ++r) {
    float s = blockSum16(ww * rv[r], red);
    if (t == 0) ws[WS_ST + b * 8 + 4 + r] = s;
  }
}

// 7) memory_new (elementwise, float4)
__global__ __launch_bounds__(256) void k_memnew(const float* __restrict__ mem,
                                                const float* __restrict__ ws,
                                                float* __restrict__ omem) {
  const size_t i = (size_t)blockIdx.x * 256 + threadIdx.x; // over B*N*16 float4s
  const int w4 = (int)(i & 15);
  const size_t bn = i >> 4;
  const int b = (int)(bn >> 10);
  float ww = ws[WS_WW + bn];
  const float* f = ws + WS_IFACE + (size_t)b * IF_STRIDE;
  float4 e4 = *(const float4*)(f + IF_ERASE + (w4 << 2));
  float4 v4 = *(const float4*)(f + IF_WVEC + (w4 << 2));
  float4 m4 = ((const float4*)mem)[i];
  float4 o;
  o.x = m4.x * (1.0f - ww * e4.x) + ww * v4.x;
  o.y = m4.y * (1.0f - ww * e4.y) + ww * v4.y;
  o.z = m4.z * (1.0f - ww * e4.z) + ww * v4.z;
  o.w = m4.w * (1.0f - ww * e4.w) + ww * v4.w;
  ((float4*)omem)[i] = o;
}

// 8) link pass: one read of link. Block = (rowgroup of 128 rows, b).
//    Broadcast operands v[j][k]/u[i][k] come through the SCALAR pipe
//    (wave-uniform loads -> s_load_dwordx8), no readlane, no hazards.
__global__ __launch_bounds__(256) void k_link(const float* __restrict__ link,
                                              float* __restrict__ ws) {
  __shared__ float tiles[4][4096];
  const int rg = blockIdx.x;      // 0..7
  const int b = blockIdx.y;       // 0..63
  const int wv = threadIdx.x >> 6;
  const int lane = threadIdx.x & 63;
  float* tile = tiles[wv];
  const float* L = link + ((size_t)b << 20);
  const float* V = ws + WS_V + ((size_t)b << 13);
  const int i0 = rg << 7;

  float rowAcc0[8], rowAcc1[8];
  #pragma unroll
  for (int k = 0; k < 8; ++k) { rowAcc0[k] = 0.0f; rowAcc1[k] = 0.0f; }

  #pragma unroll 1
  for (int tt = 0; tt < 4; ++tt) {
    const int j0 = (((tt << 2) + wv) << 6);
    const int j0u = __builtin_amdgcn_readfirstlane(j0);
    float colAcc[8];
    #pragma unroll
    for (int k = 0; k < 8; ++k) colAcc[k] = 0.0f;

    #pragma unroll
    for (int sb = 0; sb < 2; ++sb) {
      const int r0 = i0 + (sb << 6);
      // stage 64x64 tile (wave-private), XOR-swizzled by 16B blocks
      #pragma unroll
      for (int s = 0; s < 16; ++s) {
        int fb = lane + (s << 6);
        int row = fb >> 4, jb = fb & 15;
        float4 d = *(const float4*)(L + (size_t)(r0 + row) * 1024 + j0 + (jb << 2));
        *(float4*)(tile + (row << 6) + ((jb ^ (row & 15)) << 2)) = d;
      }
      // row pass: lane = row; v broadcast via scalar loads
      #pragma unroll
      for (int jb = 0; jb < 16; ++jb) {
        float vs[32];
        const float* vb = V + (size_t)(j0u + (jb << 2)) * 8;
        #pragma unroll
        for (int m = 0; m < 32; ++m) vs[m] = vb[m];
        float4 f4 = *(const float4*)(tile + (lane << 6) + ((jb ^ (lane & 15)) << 2));
        #pragma unroll
        for (int q = 0; q < 4; ++q) {
          float fq = (q == 0) ? f4.x : (q == 1) ? f4.y : (q == 2) ? f4.z : f4.w;
          #pragma unroll
          for (int k = 0; k < 8; ++k) {
            if (sb == 0) rowAcc0[k] = fmaf(fq, vs[(q << 3) + k], rowAcc0[k]);
            else         rowAcc1[k] = fmaf(fq, vs[(q << 3) + k], rowAcc1[k]);
          }
        }
      }
      // col pass: lane = col; u broadcast via scalar loads
      #pragma unroll
      for (int ib = 0; ib < 16; ++ib) {
        float uss[32];
        const float* ub = V + (size_t)(r0 + (ib << 2)) * 8;
        #pragma unroll
        for (int m = 0; m < 32; ++m) uss[m] = ub[m];
        #pragma unroll
        for (int q = 0; q < 4; ++q) {
          int i = (ib << 2) + q;
          float fq = tile[(i << 6) + ((((lane >> 2) ^ (i & 15)) << 2) | (lane & 3))];
          #pragma unroll
          for (int k = 0; k < 8; ++k)
            colAcc[k] = fmaf(fq, uss[(q << 3) + k], colAcc[k]);
        }
      }
    }
    // direct store of col partial for this (rg, coltile)
    float* cp = ws + WS_COLPART + ((((size_t)rg << 6) + (size_t)b) << 13) +
                (size_t)(j0 + lane) * 8;
    float4 c0 = {colAcc[0], colAcc[1], colAcc[2], colAcc[3]};
    float4 c1 = {colAcc[4], colAcc[5], colAcc[6], colAcc[7]};
    *(float4*)cp = c0;
    *(float4*)(cp + 4) = c1;
  }

  // cross-wave row reduction, direct store (block covers full row width)
  __syncthreads();
  float* red = &tiles[0][0]; // [wv][sb][row][k] = 4*2*64*8 = 4096 floats
  #pragma unroll
  for (int k = 0; k < 8; ++k) {
    red[(((wv << 1) + 0) * 64 + lane) * 8 + k] = rowAcc0[k];
    red[(((wv << 1) + 1) * 64 + lane) * 8 + k] = rowAcc1[k];
  }
  __syncthreads();
  {
    const int pair = threadIdx.x >> 1;       // 0..127 = sb*64+row
    const int kh = (threadIdx.x & 1) << 2;   // 0 or 4
    const int sb = pair >> 6, row = pair & 63;
    float4 s = {0.f, 0.f, 0.f, 0.f};
    #pragma unroll
    for (int w = 0; w < 4; ++w) {
      float4 v = *(const float4*)(red + (((w << 1) + sb) * 64 + row) * 8 + kh);
      s.x += v.x; s.y += v.y; s.z += v.z; s.w += v.w;
    }
    float* op = ws + WS_ROWAB + ((size_t)(b << 10) + i0 + (sb << 6) + row) * 8 + kh;
    *(float4*)op = s;
  }
}

// 9) read-content softmax + fwd/bwd combine -> rw_new (sums 8 col partials)
__global__ __launch_bounds__(1024) void k_final(const float* __restrict__ dout,
                                                const float* __restrict__ rw,
                                                const float* __restrict__ prec,
                                                const float* __restrict__ ws,
                                                float* __restrict__ orw) {
  __shared__ float kn[256];
  __shared__ float red[16];
  const int b = blockIdx.x, t = threadIdx.x;
  const float* f = ws + WS_IFACE + (size_t)b * IF_STRIDE;
  if (t < 256) kn[t] = f[IF_KN + t];
  __syncthreads();
  const float* Mrow = dout + O_MEM + ((size_t)(b << 10) + t) * WDIM;
  float dot0 = 0.f, dot1 = 0.f, dot2 = 0.f, dot3 = 0.f, ssq = 0.f;
  #pragma unroll
  for (int w = 0; w < 64; w += 4) {
    float4 m4 = *(const float4*)(Mrow + w);
    ssq += m4.x * m4.x + m4.y * m4.y + m4.z * m4.z + m4.w * m4.w;
    float4 k0 = *(const float4*)(&kn[w]);
    float4 k1 = *(const float4*)(&kn[64 + w]);
    float4 k2 = *(const float4*)(&kn[128 + w]);
    float4 k3 = *(const float4*)(&kn[192 + w]);
    dot0 += m4.x * k0.x + m4.y * k0.y + m4.z * k0.z + m4.w * k0.w;
    dot1 += m4.x * k1.x + m4.y * k1.y + m4.z * k1.z + m4.w * k1.w;
    dot2 += m4.x * k2.x + m4.y * k2.y + m4.z * k2.z + m4.w * k2.w;
    dot3 += m4.x * k3.x + m4.y * k3.y + m4.z * k3.z + m4.w * k3.w;
  }
  float rs = rsqrtf(ssq + EPSF);
  float sim[4] = {dot0 * rs * f[IF_RSTR + 0], dot1 * rs * f[IF_RSTR + 1],
                  dot2 * rs * f[IF_RSTR + 2], dot3 * rs * f[IF_RSTR + 3]};
  float cr[4];
  #pragma unroll
  for (int r = 0; r < 4; ++r) {
    float m = blockMax16(sim[r], red);
    float e = expf(sim[r] - m);
    float s = blockSum16(e, red);
    cr[r] = e / s;
  }
  const size_t bn = (size_t)(b << 10) + t;
  // sum the 8 column partials
  float ca[8];
  #pragma unroll
  for (int k = 0; k < 8; ++k) ca[k] = 0.0f;
  #pragma unroll
  for (int rg = 0; rg < 8; ++rg) {
    const float* p = ws + WS_COLPART + ((((size_t)rg << 6) + (size_t)b) << 13) +
                     (size_t)t * 8;
    float4 a = *(const float4*)p;
    float4 c2 = *(const float4*)(p + 4);
    ca[0] += a.x; ca[1] += a.y; ca[2] += a.z; ca[3] += a.w;
    ca[4] += c2.x; ca[5] += c2.y; ca[6] += c2.z; ca[7] += c2.w;
  }
  const float* ra = ws + WS_ROWAB + bn * 8;
  float d = ws[WS_DIAG + bn];
  float w_ = ws[WS_WW + bn];
  float pn = prec[bn];
  float4 r4 = *(const float4*)(rw + bn * 4);
  float rv[4] = {r4.x, r4.y, r4.z, r4.w};
  const float* ST = ws + WS_ST + b * 8;
  float ow = 1.0f - w_;
  float res[4];
  #pragma unroll
  for (int r = 0; r < 4; ++r) {
    float A = ra[r], Ap = ra[4 + r], Bv = ca[r], Bp = ca[4 + r];
    float fwd = ow * (A - d * rv[r]) - (Ap - w_ * d * rv[r]) + w_ * (ST[r] - pn * rv[r]);
    float bwd = ow * (Bv - d * rv[r]) - (Bp - w_ * d * rv[r]) + pn * (ST[4 + r] - w_ * rv[r]);
    res[r] = f[IF_MODES + r * 3] * bwd + f[IF_MODES + r * 3 + 1] * cr[r] +
             f[IF_MODES + r * 3 + 2] * fwd;
  }
  float4 o = {res[0], res[1], res[2], res[3]};
  *(float4*)(orw + bn * 4) = o;
}

extern "C" void kernel_launch(void* const* d_in, const int* in_sizes, int n_in,
                              void* d_out, int out_size, void* d_ws, size_t ws_size,
                              hipStream_t stream) {
  const float* x     = (const float*)d_in[0];
  const float* rw    = (const float*)d_in[1];
  const float* mem   = (const float*)d_in[2];
  const float* usage = (const float*)d_in[3];
  const float* wwp   = (const float*)d_in[4];
  const float* link  = (const float*)d_in[5];
  const float* prec  = (const float*)d_in[6];
  const float* W1    = (const float*)d_in[7];
  const float* b1    = (const float*)d_in[8];
  const float* Wo    = (const float*)d_in[9];
  const float* bo    = (const float*)d_in[10];
  const float* Wr    = (const float*)d_in[11];
  const float* br    = (const float*)d_in[12];
  const float* Wxi   = (const float*)d_in[13];
  const float* bxi   = (const float*)d_in[14];
  float* out = (float*)d_out;
  float* ws = (float*)d_ws;

  k_read_flat<<<dim3(4, 64), 1024, 0, stream>>>(mem, rw, ws);
  k_h<<<64, 512, 0, stream>>>(x, W1, b1, ws);
  k_xi<<<64, 512, 0, stream>>>(Wxi, bxi, ws, out);
  k_out<<<64, 256, 0, stream>>>(Wo, bo, Wr, br, ws, out);
  k_alloc<<<64, 512, 0, stream>>>(rw, usage, wwp, ws, out + O_USAGE);
  k_wcww<<<64, 1024, 0, stream>>>(mem, rw, prec, link, ws);
  k_memnew<<<4096, 256, 0, stream>>>(mem, ws, out + O_MEM);
  k_link<<<dim3(8, 64), 256, 0, stream>>>(link, ws);
  k_final<<<64, 1024, 0, stream>>>(out, rw, prec, ws, out + O_RW);
}

// Round 4
// 440.690 us; speedup vs baseline: 1.2469x; 1.2469x over previous
//
#include <hip/hip_runtime.h>

#define NB 64
#define NN 1024
#define WDIM 64
#define RR 4
#define HID 512
#define XID 471
#define EPSF 1e-6f

// ---- d_out offsets (floats) ----
#define O_OUT   0
#define O_XI    16384
#define O_RW    46528
#define O_MEM   308672
#define O_USAGE 4502976

// ---- ws offsets (floats) ----
#define WS_RFPART   0          // [4][64][256] read_flat partials
#define WS_IFACE    98304      // [64][480]
#define WS_ALLOC    129024     // [64][1024]
#define WS_WW       194560     // [64][1024]
#define WS_V        260096     // [64][1024][8]
#define WS_ST       784384     // [64][8]
#define WS_DIAG     784896     // [64][1024]
#define WS_ROWAB    850432     // [64][1024][8]
#define WS_COLPART  1899008    // [8][64][1024][8] col partials (16.8 MB)

// ---- iface per-b layout (stride 480) ----
#define IF_KN     0
#define IF_WKN    256
#define IF_ERASE  320
#define IF_WVEC   384
#define IF_RSTR   448
#define IF_FREE   452
#define IF_WSTR   456
#define IF_AG     457
#define IF_WG     458
#define IF_MODES  460
#define IF_STRIDE 480

__device__ __forceinline__ float sigmoidf_(float x) { return 1.0f / (1.0f + expf(-x)); }
__device__ __forceinline__ float oneplusf_(float x) {
  return 1.0f + ((x > 20.0f) ? x : log1pf(expf(x)));
}
__device__ __forceinline__ float readlane_f(float v, int l) {
  return __int_as_float(__builtin_amdgcn_readlane(__float_as_int(v), l));
}

// block reductions for 16-wave (1024-thread) blocks
__device__ __forceinline__ float blockSum16(float v, float* red) {
  #pragma unroll
  for (int s = 32; s; s >>= 1) v += __shfl_xor(v, s);
  __syncthreads();
  if ((threadIdx.x & 63) == 0) red[threadIdx.x >> 6] = v;
  __syncthreads();
  float s = 0.0f;
  #pragma unroll
  for (int i = 0; i < 16; ++i) s += red[i];
  return s;
}
__device__ __forceinline__ float blockMax16(float v, float* red) {
  #pragma unroll
  for (int s = 32; s; s >>= 1) v = fmaxf(v, __shfl_xor(v, s));
  __syncthreads();
  if ((threadIdx.x & 63) == 0) red[threadIdx.x >> 6] = v;
  __syncthreads();
  float m = red[0];
  #pragma unroll
  for (int i = 1; i < 16; ++i) m = fmaxf(m, red[i]);
  return m;
}

// 1) read_flat partials: part[q][b][r*64+w] = sum_{n in q-range} M[b,n,w]*rw[b,n,r]
__global__ __launch_bounds__(1024) void k_read_flat(const float* __restrict__ mem,
                                                    const float* __restrict__ rw,
                                                    float* __restrict__ ws) {
  __shared__ float red[1024];
  const int q = blockIdx.x, b = blockIdx.y, t = threadIdx.x;
  const int rwi = t & 255;
  const int r = rwi >> 6, w = rwi & 63;
  const int ng = t >> 8;
  const int n0 = (q << 8) + (ng << 6);
  const float* M  = mem + ((size_t)(b << 10) + n0) * WDIM;
  const float* Rw = rw  + ((size_t)(b << 10) + n0) * RR;
  float a0 = 0.f, a1 = 0.f, a2 = 0.f, a3 = 0.f;
  for (int n = 0; n < 64; n += 4) {
    a0 += M[(n + 0) * WDIM + w] * Rw[(n + 0) * RR + r];
    a1 += M[(n + 1) * WDIM + w] * Rw[(n + 1) * RR + r];
    a2 += M[(n + 2) * WDIM + w] * Rw[(n + 2) * RR + r];
    a3 += M[(n + 3) * WDIM + w] * Rw[(n + 3) * RR + r];
  }
  red[t] = (a0 + a1) + (a2 + a3);
  __syncthreads();
  if (t < 256)
    ws[WS_RFPART + (((q << 6) + b) << 8) + t] =
        red[t] + red[t + 256] + red[t + 512] + red[t + 768];
}

// 2) fused MLP: h (LDS-resident) -> output, xi, interface activations
__global__ __launch_bounds__(512) void k_mlp(const float* __restrict__ x,
                                             const float* __restrict__ W1,
                                             const float* __restrict__ b1,
                                             const float* __restrict__ Wo,
                                             const float* __restrict__ bo,
                                             const float* __restrict__ Wr,
                                             const float* __restrict__ br,
                                             const float* __restrict__ Wxi,
                                             const float* __restrict__ bxi,
                                             float* __restrict__ ws,
                                             float* __restrict__ out) {
  __shared__ float cat[768];
  __shared__ float h[512];
  __shared__ float xs[XID];
  const int b = blockIdx.x, t = threadIdx.x;
  cat[t] = x[b * 512 + t];
  if (t < 256) {
    float s = 0.0f;
    #pragma unroll
    for (int q = 0; q < 4; ++q) s += ws[WS_RFPART + (((q << 6) + b) << 8) + t];
    cat[512 + t] = s;
  }
  __syncthreads();
  {
    float acc = b1[t];
    #pragma unroll 2
    for (int k = 0; k < 768; k += 4) {
      acc += cat[k] * W1[k * 512 + t];
      acc += cat[k + 1] * W1[(k + 1) * 512 + t];
      acc += cat[k + 2] * W1[(k + 2) * 512 + t];
      acc += cat[k + 3] * W1[(k + 3) * 512 + t];
    }
    h[t] = fmaxf(acc, 0.0f);
  }
  __syncthreads();
  if (t < 256) {
    float acc = bo[t] + br[t];
    #pragma unroll 4
    for (int j = 0; j < 512; ++j) acc += h[j] * Wo[j * 256 + t];
    #pragma unroll 4
    for (int j = 0; j < 256; ++j) acc += cat[512 + j] * Wr[j * 256 + t];
    out[O_OUT + b * 256 + t] = acc;
  } else {
    const int c = t - 256;  // xi cols 0..255
    float acc = bxi[c];
    #pragma unroll 4
    for (int j = 0; j < 512; ++j) acc += h[j] * Wxi[j * XID + c];
    out[O_XI + b * XID + c] = acc;
    xs[c] = acc;
  }
  if (t >= 297) {
    const int c = t - 41;   // xi cols 256..470
    float acc = bxi[c];
    #pragma unroll 4
    for (int j = 0; j < 512; ++j) acc += h[j] * Wxi[j * XID + c];
    out[O_XI + b * XID + c] = acc;
    xs[c] = acc;
  }
  __syncthreads();
  if (t < 64) {
    const int w = t;
    float* f = ws + WS_IFACE + (size_t)b * IF_STRIDE;
    #pragma unroll
    for (int r = 0; r < 4; ++r) {
      float kv = xs[r * 64 + w];
      float ss = kv * kv;
      #pragma unroll
      for (int s = 32; s; s >>= 1) ss += __shfl_xor(ss, s);
      f[IF_KN + r * 64 + w] = kv * rsqrtf(ss + EPSF);
    }
    {
      float kv = xs[260 + w];
      float ss = kv * kv;
      #pragma unroll
      for (int s = 32; s; s >>= 1) ss += __shfl_xor(ss, s);
      f[IF_WKN + w] = kv * rsqrtf(ss + EPSF);
    }
    f[IF_ERASE + w] = sigmoidf_(xs[325 + w]);
    f[IF_WVEC + w] = xs[389 + w];
    if (w < 4) {
      f[IF_RSTR + w] = oneplusf_(xs[256 + w]);
      f[IF_FREE + w] = sigmoidf_(xs[453 + w]);
      float a = xs[459 + w * 3], bb = xs[459 + w * 3 + 1], c = xs[459 + w * 3 + 2];
      float m = fmaxf(a, fmaxf(bb, c));
      float ea = expf(a - m), eb = expf(bb - m), ec = expf(c - m);
      float s = ea + eb + ec;
      f[IF_MODES + w * 3] = ea / s;
      f[IF_MODES + w * 3 + 1] = eb / s;
      f[IF_MODES + w * 3 + 2] = ec / s;
    }
    if (w == 0) {
      f[IF_WSTR] = oneplusf_(xs[324]);
      f[IF_AG] = sigmoidf_(xs[457]);
      f[IF_WG] = sigmoidf_(xs[458]);
    }
  }
}

// 3) usage_new (fused) + allocation: bitonic sort + product scan + scatter
__global__ __launch_bounds__(512) void k_alloc(const float* __restrict__ rw,
                                               const float* __restrict__ usage,
                                               const float* __restrict__ wwp,
                                               float* __restrict__ ws,
                                               float* __restrict__ ousage) {
  __shared__ float us[1024];
  __shared__ int idx[1024];
  __shared__ float cp[2][1024];
  const int b = blockIdx.x, t = threadIdx.x;
  const float* fr = ws + WS_IFACE + (size_t)b * IF_STRIDE + IF_FREE;
  const float f0 = fr[0], f1 = fr[1], f2 = fr[2], f3 = fr[3];
  #pragma unroll
  for (int hh = 0; hh < 2; ++hh) {
    const int n = t + (hh << 9);
    const int i = (b << 10) + n;
    const float4 r4 = *(const float4*)(rw + (size_t)i * 4);
    float ret = (1.0f - f0 * r4.x) * (1.0f - f1 * r4.y) *
                (1.0f - f2 * r4.z) * (1.0f - f3 * r4.w);
    float u = usage[i], w = wwp[i];
    float un = (u + w - u * w) * ret;
    ousage[i] = un;
    us[n] = un;
    idx[n] = n;
  }
  __syncthreads();
  for (int k = 2; k <= 1024; k <<= 1) {
    for (int j = k >> 1; j > 0; j >>= 1) {
      int i = ((t & ~(j - 1)) << 1) | (t & (j - 1));
      int ix = i | j;
      bool up = ((i & k) == 0);
      float a = us[i], c = us[ix];
      int ia = idx[i], ic = idx[ix];
      bool gt = (a > c) || (a == c && ia > ic);
      if (gt == up) { us[i] = c; us[ix] = a; idx[i] = ic; idx[ix] = ia; }
      __syncthreads();
    }
  }
  cp[0][t] = us[t];
  cp[0][t + 512] = us[t + 512];
  __syncthreads();
  int src = 0;
  for (int off = 1; off < 1024; off <<= 1) {
    int dst = src ^ 1;
    for (int e = t; e < 1024; e += 512)
      cp[dst][e] = (e >= off) ? cp[src][e] * cp[src][e - off] : cp[src][e];
    __syncthreads();
    src = dst;
  }
  for (int e = t; e < 1024; e += 512) {
    float cpe = (e == 0) ? 1.0f : cp[src][e - 1];
    ws[WS_ALLOC + (b << 10) + idx[e]] = (1.0f - us[e]) * cpe;
  }
}

// 4) write-content softmax + ww + v-vectors + S/T + diag + memory_new (fused)
__global__ __launch_bounds__(1024) void k_wcww(const float* __restrict__ mem,
                                               const float* __restrict__ rw,
                                               const float* __restrict__ prec,
                                               const float* __restrict__ link,
                                               float* __restrict__ ws,
                                               float* __restrict__ omem) {
  __shared__ float wkn[64];
  __shared__ float red[16];
  __shared__ float redST[128];
  __shared__ float sh_ev[128];  // erase [0..63], wvec [64..127]
  const int b = blockIdx.x, t = threadIdx.x;
  const float* f = ws + WS_IFACE + (size_t)b * IF_STRIDE;
  if (t < 64) wkn[t] = f[IF_WKN + t];
  else if (t < 128) sh_ev[t - 64] = f[IF_ERASE + (t - 64)];
  else if (t < 192) sh_ev[64 + (t - 128)] = f[IF_WVEC + (t - 128)];
  __syncthreads();
  const float* Mrow = mem + ((size_t)(b << 10) + t) * WDIM;
  float dot = 0.0f, ssq = 0.0f;
  #pragma unroll
  for (int w = 0; w < 64; w += 4) {
    float4 m4 = *(const float4*)(Mrow + w);
    float4 k4 = *(const float4*)(&wkn[w]);
    dot += m4.x * k4.x + m4.y * k4.y + m4.z * k4.z + m4.w * k4.w;
    ssq += m4.x * m4.x + m4.y * m4.y + m4.z * m4.z + m4.w * m4.w;
  }
  float sim = dot * rsqrtf(ssq + EPSF) * f[IF_WSTR];
  float bmax = blockMax16(sim, red);
  float e = expf(sim - bmax);
  float bsum = blockSum16(e, red);
  float wc = e / bsum;
  float ag = f[IF_AG], wg = f[IF_WG];
  float ww = wg * (ag * ws[WS_ALLOC + (b << 10) + t] + (1.0f - ag) * wc);
  ws[WS_WW + (b << 10) + t] = ww;
  float4 r4 = *(const float4*)(rw + ((size_t)(b << 10) + t) * 4);
  float* vp = ws + WS_V + ((size_t)(b << 10) + t) * 8;
  float4 v0 = {r4.x, r4.y, r4.z, r4.w};
  float4 v1 = {ww * r4.x, ww * r4.y, ww * r4.z, ww * r4.w};
  *(float4*)vp = v0;
  *(float4*)(vp + 4) = v1;
  ws[WS_DIAG + (b << 10) + t] = link[((size_t)(b << 10) + t) * 1024 + t];
  // 8 block sums with ONE barrier: {p*rv[0..3], ww*rv[0..3]}
  float p = prec[(b << 10) + t];
  float vals[8] = {p * r4.x, p * r4.y, p * r4.z, p * r4.w,
                   ww * r4.x, ww * r4.y, ww * r4.z, ww * r4.w};
  #pragma unroll
  for (int k = 0; k < 8; ++k) {
    float v = vals[k];
    #pragma unroll
    for (int s = 32; s; s >>= 1) v += __shfl_xor(v, s);
    vals[k] = v;
  }
  if ((t & 63) == 0) {
    #pragma unroll
    for (int k = 0; k < 8; ++k) redST[(t >> 6) * 8 + k] = vals[k];
  }
  __syncthreads();
  if (t < 8) {
    float s = 0.0f;
    #pragma unroll
    for (int w = 0; w < 16; ++w) s += redST[w * 8 + t];
    ws[WS_ST + b * 8 + t] = s;
  }
  // fused memory_new for this row (mem row is L1/L2-hot from the dot pass)
  float* Orow = omem + ((size_t)(b << 10) + t) * WDIM;
  #pragma unroll
  for (int w4 = 0; w4 < 16; ++w4) {
    float4 m4 = *(const float4*)(Mrow + (w4 << 2));
    float4 e4 = *(const float4*)(&sh_ev[w4 << 2]);
    float4 w4v = *(const float4*)(&sh_ev[64 + (w4 << 2)]);
    float4 o;
    o.x = m4.x * (1.0f - ww * e4.x) + ww * w4v.x;
    o.y = m4.y * (1.0f - ww * e4.y) + ww * w4v.y;
    o.z = m4.z * (1.0f - ww * e4.z) + ww * w4v.z;
    o.w = m4.w * (1.0f - ww * e4.w) + ww * w4v.w;
    *(float4*)(Orow + (w4 << 2)) = o;
  }
}

// 5) link pass: block = (rowgroup of 128 rows, b) covering ALL 1024 cols.
//    Double-buffered block tile [2][128][64] with register prefetch (T14):
//    issue loads for tile jt+1 BEFORE computing tile jt; ds_write after.
//    waves 0,1: row pass (lane=row) -> complete rowAB, direct store.
//    waves 2,3: col pass (lane=col, uniform-index readlane) -> colpart[rg].
__global__ __launch_bounds__(256) void k_link(const float* __restrict__ link,
                                              float* __restrict__ ws) {
  __shared__ float buf[2][8192];   // [2][128][64]
  __shared__ float scr[2][512];    // [2][8][64]  (k-major, conflict-free)
  const int rg = blockIdx.x;       // 0..7
  const int b = blockIdx.y;        // 0..63
  const int wv = threadIdx.x >> 6, lane = threadIdx.x & 63;
  const int i0 = rg << 7;
  const float* L = link + ((size_t)b << 20) + (size_t)i0 * 1024;
  const float* V = ws + WS_V + ((size_t)b << 13);

  // staging: this lane handles 8 segments (4 rows x 256B each instr)
  const float* sga[8];
  int sdst[8];
  {
    const int cb = lane & 15;
    #pragma unroll
    for (int q = 0; q < 8; ++q) {
      const int s = (wv << 3) + q;
      const int row = (s << 2) + (lane >> 4);
      sga[q] = L + (size_t)row * 1024 + (cb << 2);
      sdst[q] = (row << 6) + ((cb ^ (row & 15)) << 2);
    }
  }

  float rowAcc[8], colAcc[8], u[8], vvc[8], vvn[8];
  #pragma unroll
  for (int k = 0; k < 8; ++k) { rowAcc[k] = 0.0f; colAcc[k] = 0.0f; }
  if (wv < 2) {
    const float* vp0 = V + (size_t)lane * 8;
    float4 a = *(const float4*)vp0, c = *(const float4*)(vp0 + 4);
    vvc[0]=a.x; vvc[1]=a.y; vvc[2]=a.z; vvc[3]=a.w;
    vvc[4]=c.x; vvc[5]=c.y; vvc[6]=c.z; vvc[7]=c.w;
  } else {
    const float* up = V + (size_t)(i0 + ((wv - 2) << 6) + lane) * 8;
    float4 a = *(const float4*)up, c = *(const float4*)(up + 4);
    u[0]=a.x; u[1]=a.y; u[2]=a.z; u[3]=a.w;
    u[4]=c.x; u[5]=c.y; u[6]=c.z; u[7]=c.w;
  }

  // prologue: stage tile 0
  {
    float4 pre[8];
    #pragma unroll
    for (int q = 0; q < 8; ++q) pre[q] = *(const float4*)(sga[q]);
    #pragma unroll
    for (int q = 0; q < 8; ++q) *(float4*)(&buf[0][sdst[q]]) = pre[q];
  }
  __syncthreads();

  int p = 0;
  #pragma unroll 1
  for (int jt = 0; jt < 16; ++jt) {
    // A) prefetch next tile (+ next v-strip for row waves)
    float4 pre[8];
    if (jt < 15) {
      #pragma unroll
      for (int q = 0; q < 8; ++q) pre[q] = *(const float4*)(sga[q] + ((jt + 1) << 6));
      if (wv < 2) {
        const float* vp = V + (size_t)((((jt + 1) << 6)) + lane) * 8;
        float4 a = *(const float4*)vp, c = *(const float4*)(vp + 4);
        vvn[0]=a.x; vvn[1]=a.y; vvn[2]=a.z; vvn[3]=a.w;
        vvn[4]=c.x; vvn[5]=c.y; vvn[6]=c.z; vvn[7]=c.w;
      }
    }
    // B) compute on buf[p]
    const float* tb = buf[p];
    if (wv < 2) {
      const int rr = (wv << 6) + lane;
      const float* base = tb + (rr << 6);
      const int rm = rr & 15;
      #pragma unroll
      for (int jb = 0; jb < 16; ++jb) {
        float4 f4 = *(const float4*)(base + ((jb ^ rm) << 2));
        #pragma unroll
        for (int q = 0; q < 4; ++q) {
          float fq = (q == 0) ? f4.x : (q == 1) ? f4.y : (q == 2) ? f4.z : f4.w;
          const int j = (jb << 2) + q;
          #pragma unroll
          for (int k = 0; k < 8; ++k)
            rowAcc[k] = fmaf(fq, readlane_f(vvc[k], j), rowAcc[k]);
        }
      }
    } else {
      const int rr0 = (wv - 2) << 6;
      #pragma unroll 8
      for (int i = 0; i < 64; ++i) {
        const int rr = rr0 + i;
        float fq = tb[(rr << 6) + ((((lane >> 2) ^ (rr & 15)) << 2) | (lane & 3))];
        #pragma unroll
        for (int k = 0; k < 8; ++k)
          colAcc[k] = fmaf(fq, readlane_f(u[k], i), colAcc[k]);
      }
      if (wv == 3) {
        #pragma unroll
        for (int k = 0; k < 8; ++k) scr[p][(k << 6) + lane] = colAcc[k];
      }
    }
    __syncthreads();  // compute done; scr[p] visible
    // C) wave2: combine halves, store col partial
    if (wv == 2) {
      float* cp = ws + WS_COLPART + ((((size_t)rg << 6) + (size_t)b) << 13) +
                  (size_t)((jt << 6) + lane) * 8;
      float s0 = colAcc[0] + scr[p][(0 << 6) + lane];
      float s1 = colAcc[1] + scr[p][(1 << 6) + lane];
      float s2 = colAcc[2] + scr[p][(2 << 6) + lane];
      float s3 = colAcc[3] + scr[p][(3 << 6) + lane];
      float s4 = colAcc[4] + scr[p][(4 << 6) + lane];
      float s5 = colAcc[5] + scr[p][(5 << 6) + lane];
      float s6 = colAcc[6] + scr[p][(6 << 6) + lane];
      float s7 = colAcc[7] + scr[p][(7 << 6) + lane];
      float4 c0 = {s0, s1, s2, s3}, c1 = {s4, s5, s6, s7};
      *(float4*)cp = c0;
      *(float4*)(cp + 4) = c1;
    }
    if (wv >= 2) {
      #pragma unroll
      for (int k = 0; k < 8; ++k) colAcc[k] = 0.0f;
    }
    // D) write prefetched tile into the other buffer
    if (jt < 15) {
      #pragma unroll
      for (int q = 0; q < 8; ++q) *(float4*)(&buf[p ^ 1][sdst[q]]) = pre[q];
      if (wv < 2) {
        #pragma unroll
        for (int k = 0; k < 8; ++k) vvc[k] = vvn[k];
      }
    }
    __syncthreads();  // buf[p^1] ready
    p ^= 1;
  }
  if (wv < 2) {
    float* rp = ws + WS_ROWAB + ((size_t)(b << 10) + i0 + (wv << 6) + lane) * 8;
    float4 c0 = {rowAcc[0], rowAcc[1], rowAcc[2], rowAcc[3]};
    float4 c1 = {rowAcc[4], rowAcc[5], rowAcc[6], rowAcc[7]};
    *(float4*)rp = c0;
    *(float4*)(rp + 4) = c1;
  }
}

// 6) read-content softmax + fwd/bwd combine -> rw_new (sums 8 col partials)
__global__ __launch_bounds__(1024) void k_final(const float* __restrict__ dout,
                                                const float* __restrict__ rw,
                                                const float* __restrict__ prec,
                                                const float* __restrict__ ws,
                                                float* __restrict__ orw) {
  __shared__ float kn[256];
  __shared__ float red[16];
  const int b = blockIdx.x, t = threadIdx.x;
  const float* f = ws + WS_IFACE + (size_t)b * IF_STRIDE;
  if (t < 256) kn[t] = f[IF_KN + t];
  __syncthreads();
  const float* Mrow = dout + O_MEM + ((size_t)(b << 10) + t) * WDIM;
  float dot0 = 0.f, dot1 = 0.f, dot2 = 0.f, dot3 = 0.f, ssq = 0.f;
  #pragma unroll
  for (int w = 0; w < 64; w += 4) {
    float4 m4 = *(const float4*)(Mrow + w);
    ssq += m4.x * m4.x + m4.y * m4.y + m4.z * m4.z + m4.w * m4.w;
    float4 k0 = *(const float4*)(&kn[w]);
    float4 k1 = *(const float4*)(&kn[64 + w]);
    float4 k2 = *(const float4*)(&kn[128 + w]);
    float4 k3 = *(const float4*)(&kn[192 + w]);
    dot0 += m4.x * k0.x + m4.y * k0.y + m4.z * k0.z + m4.w * k0.w;
    dot1 += m4.x * k1.x + m4.y * k1.y + m4.z * k1.z + m4.w * k1.w;
    dot2 += m4.x * k2.x + m4.y * k2.y + m4.z * k2.z + m4.w * k2.w;
    dot3 += m4.x * k3.x + m4.y * k3.y + m4.z * k3.z + m4.w * k3.w;
  }
  float rs = rsqrtf(ssq + EPSF);
  float sim[4] = {dot0 * rs * f[IF_RSTR + 0], dot1 * rs * f[IF_RSTR + 1],
                  dot2 * rs * f[IF_RSTR + 2], dot3 * rs * f[IF_RSTR + 3]};
  float cr[4];
  #pragma unroll
  for (int r = 0; r < 4; ++r) {
    float m = blockMax16(sim[r], red);
    float e = expf(sim[r] - m);
    float s = blockSum16(e, red);
    cr[r] = e / s;
  }
  const size_t bn = (size_t)(b << 10) + t;
  float ca[8];
  #pragma unroll
  for (int k = 0; k < 8; ++k) ca[k] = 0.0f;
  #pragma unroll
  for (int rg = 0; rg < 8; ++rg) {
    const float* p = ws + WS_COLPART + ((((size_t)rg << 6) + (size_t)b) << 13) +
                     (size_t)t * 8;
    float4 a = *(const float4*)p;
    float4 c2 = *(const float4*)(p + 4);
    ca[0] += a.x; ca[1] += a.y; ca[2] += a.z; ca[3] += a.w;
    ca[4] += c2.x; ca[5] += c2.y; ca[6] += c2.z; ca[7] += c2.w;
  }
  const float* ra = ws + WS_ROWAB + bn * 8;
  float d = ws[WS_DIAG + bn];
  float w_ = ws[WS_WW + bn];
  float pn = prec[bn];
  float4 r4 = *(const float4*)(rw + bn * 4);
  float rv[4] = {r4.x, r4.y, r4.z, r4.w};
  const float* ST = ws + WS_ST + b * 8;
  float ow = 1.0f - w_;
  float res[4];
  #pragma unroll
  for (int r = 0; r < 4; ++r) {
    float A = ra[r], Ap = ra[4 + r], Bv = ca[r], Bp = ca[4 + r];
    float fwd = ow * (A - d * rv[r]) - (Ap - w_ * d * rv[r]) + w_ * (ST[r] - pn * rv[r]);
    float bwd = ow * (Bv - d * rv[r]) - (Bp - w_ * d * rv[r]) + pn * (ST[4 + r] - w_ * rv[r]);
    res[r] = f[IF_MODES + r * 3] * bwd + f[IF_MODES + r * 3 + 1] * cr[r] +
             f[IF_MODES + r * 3 + 2] * fwd;
  }
  float4 o = {res[0], res[1], res[2], res[3]};
  *(float4*)(orw + bn * 4) = o;
}

extern "C" void kernel_launch(void* const* d_in, const int* in_sizes, int n_in,
                              void* d_out, int out_size, void* d_ws, size_t ws_size,
                              hipStream_t stream) {
  const float* x     = (const float*)d_in[0];
  const float* rw    = (const float*)d_in[1];
  const float* mem   = (const float*)d_in[2];
  const float* usage = (const float*)d_in[3];
  const float* wwp   = (const float*)d_in[4];
  const float* link  = (const float*)d_in[5];
  const float* prec  = (const float*)d_in[6];
  const float* W1    = (const float*)d_in[7];
  const float* b1    = (const float*)d_in[8];
  const float* Wo    = (const float*)d_in[9];
  const float* bo    = (const float*)d_in[10];
  const float* Wr    = (const float*)d_in[11];
  const float* br    = (const float*)d_in[12];
  const float* Wxi   = (const float*)d_in[13];
  const float* bxi   = (const float*)d_in[14];
  float* out = (float*)d_out;
  float* ws = (float*)d_ws;

  k_read_flat<<<dim3(4, 64), 1024, 0, stream>>>(mem, rw, ws);
  k_mlp<<<64, 512, 0, stream>>>(x, W1, b1, Wo, bo, Wr, br, Wxi, bxi, ws, out);
  k_alloc<<<64, 512, 0, stream>>>(rw, usage, wwp, ws, out + O_USAGE);
  k_wcww<<<64, 1024, 0, stream>>>(mem, rw, prec, link, ws, out + O_MEM);
  k_link<<<dim3(8, 64), 256, 0, stream>>>(link, ws);
  k_final<<<64, 1024, 0, stream>>>(out, rw, prec, ws, out + O_RW);
}

// Round 5
// 360.494 us; speedup vs baseline: 1.5243x; 1.2225x over previous
//
#include <hip/hip_runtime.h>

#define NB 64
#define NN 1024
#define WDIM 64
#define RR 4
#define HID 512
#define XID 471
#define EPSF 1e-6f

// ---- d_out offsets (floats) ----
#define O_OUT   0
#define O_XI    16384
#define O_RW    46528
#define O_MEM   308672
#define O_USAGE 4502976

// ---- ws offsets (floats) ----
#define WS_RFPART   0          // [4][64][256] read_flat partials
#define WS_H        65536      // [64][512]
#define WS_IFACE    98304      // [64][480]
#define WS_ALLOC    129024     // [64][1024]
#define WS_WW       194560     // [64][1024]
#define WS_V        260096     // [64][1024][8]
#define WS_ST       784384     // [64][8]
#define WS_DIAG     784896     // [64][1024]
#define WS_ROWAB    850432     // [64][1024][8]
#define WS_COLPART  1899008    // [8][64][1024][8] col partials (16.8 MB)

// ---- iface per-b layout (stride 480) ----
#define IF_KN     0
#define IF_WKN    256
#define IF_ERASE  320
#define IF_WVEC   384
#define IF_RSTR   448
#define IF_FREE   452
#define IF_WSTR   456
#define IF_AG     457
#define IF_WG     458
#define IF_MODES  460
#define IF_STRIDE 480

__device__ __forceinline__ float sigmoidf_(float x) { return 1.0f / (1.0f + expf(-x)); }
__device__ __forceinline__ float oneplusf_(float x) {
  return 1.0f + ((x > 20.0f) ? x : log1pf(expf(x)));
}
__device__ __forceinline__ float readlane_f(float v, int l) {
  return __int_as_float(__builtin_amdgcn_readlane(__float_as_int(v), l));
}

typedef const __attribute__((address_space(1))) void gas_void;
typedef __attribute__((address_space(3))) void las_void;
__device__ __forceinline__ void gl16(const float* g, float* l) {
  __builtin_amdgcn_global_load_lds((gas_void*)g, (las_void*)l, 16, 0, 0);
}

// 1) read_flat partials
__global__ __launch_bounds__(1024) void k_read_flat(const float* __restrict__ mem,
                                                    const float* __restrict__ rw,
                                                    float* __restrict__ ws) {
  __shared__ float red[1024];
  const int q = blockIdx.x, b = blockIdx.y, t = threadIdx.x;
  const int rwi = t & 255;
  const int r = rwi >> 6, w = rwi & 63;
  const int ng = t >> 8;
  const int n0 = (q << 8) + (ng << 6);
  const float* M  = mem + ((size_t)(b << 10) + n0) * WDIM;
  const float* Rw = rw  + ((size_t)(b << 10) + n0) * RR;
  float a0 = 0.f, a1 = 0.f, a2 = 0.f, a3 = 0.f;
  for (int n = 0; n < 64; n += 4) {
    a0 += M[(n + 0) * WDIM + w] * Rw[(n + 0) * RR + r];
    a1 += M[(n + 1) * WDIM + w] * Rw[(n + 1) * RR + r];
    a2 += M[(n + 2) * WDIM + w] * Rw[(n + 2) * RR + r];
    a3 += M[(n + 3) * WDIM + w] * Rw[(n + 3) * RR + r];
  }
  red[t] = (a0 + a1) + (a2 + a3);
  __syncthreads();
  if (t < 256)
    ws[WS_RFPART + (((q << 6) + b) << 8) + t] =
        red[t] + red[t + 256] + red[t + 512] + red[t + 768];
}

// 2) h = relu([x, read_flat] @ W1 + b1), col-split grid (2,64)
__global__ __launch_bounds__(256) void k_h(const float* __restrict__ x,
                                           const float* __restrict__ W1,
                                           const float* __restrict__ b1,
                                           float* __restrict__ ws) {
  __shared__ float cat[768];
  const int ch = blockIdx.x, b = blockIdx.y, t = threadIdx.x;
  cat[t] = x[b * 512 + t];
  cat[256 + t] = x[b * 512 + 256 + t];
  {
    float s = 0.0f;
    #pragma unroll
    for (int q = 0; q < 4; ++q) s += ws[WS_RFPART + (((q << 6) + b) << 8) + t];
    cat[512 + t] = s;
  }
  __syncthreads();
  const int col = (ch << 8) + t;
  float acc = b1[col];
  #pragma unroll 4
  for (int k = 0; k < 768; ++k) acc += cat[k] * W1[k * 512 + col];
  ws[WS_H + b * 512 + col] = fmaxf(acc, 0.0f);
}

// 3) output = h@Wo + bo + read_flat@Wr + br
__global__ __launch_bounds__(256) void k_out(const float* __restrict__ Wo,
                                             const float* __restrict__ bo,
                                             const float* __restrict__ Wr,
                                             const float* __restrict__ br,
                                             const float* __restrict__ ws,
                                             float* __restrict__ out) {
  __shared__ float h[512];
  __shared__ float rf[256];
  const int b = blockIdx.x, t = threadIdx.x;
  h[t] = ws[WS_H + b * 512 + t];
  h[256 + t] = ws[WS_H + b * 512 + 256 + t];
  {
    float s = 0.0f;
    #pragma unroll
    for (int q = 0; q < 4; ++q) s += ws[WS_RFPART + (((q << 6) + b) << 8) + t];
    rf[t] = s;
  }
  __syncthreads();
  float acc = bo[t] + br[t];
  #pragma unroll 4
  for (int j = 0; j < 512; ++j) acc += h[j] * Wo[j * 256 + t];
  #pragma unroll 4
  for (int j = 0; j < 256; ++j) acc += rf[j] * Wr[j * 256 + t];
  out[O_OUT + b * 256 + t] = acc;
}

// 4) xi = h@Wxi + bxi, col-split grid (2,64)
__global__ __launch_bounds__(256) void k_xi(const float* __restrict__ Wxi,
                                            const float* __restrict__ bxi,
                                            const float* __restrict__ ws,
                                            float* __restrict__ out) {
  __shared__ float h[512];
  const int ch = blockIdx.x, b = blockIdx.y, t = threadIdx.x;
  h[t] = ws[WS_H + b * 512 + t];
  h[256 + t] = ws[WS_H + b * 512 + 256 + t];
  __syncthreads();
  const int col = (ch << 8) + t;
  if (col < XID) {
    float acc = bxi[col];
    #pragma unroll 4
    for (int j = 0; j < 512; ++j) acc += h[j] * Wxi[j * XID + col];
    out[O_XI + b * XID + col] = acc;
  }
}

// 5) interface activations (one wave per b)
__global__ __launch_bounds__(64) void k_iface(const float* __restrict__ out,
                                              float* __restrict__ ws) {
  const int b = blockIdx.x, w = threadIdx.x;
  const float* xi = out + O_XI + b * XID;
  float* f = ws + WS_IFACE + (size_t)b * IF_STRIDE;
  #pragma unroll
  for (int r = 0; r < 4; ++r) {
    float kv = xi[r * 64 + w];
    float ss = kv * kv;
    #pragma unroll
    for (int s = 32; s; s >>= 1) ss += __shfl_xor(ss, s);
    f[IF_KN + r * 64 + w] = kv * rsqrtf(ss + EPSF);
  }
  {
    float kv = xi[260 + w];
    float ss = kv * kv;
    #pragma unroll
    for (int s = 32; s; s >>= 1) ss += __shfl_xor(ss, s);
    f[IF_WKN + w] = kv * rsqrtf(ss + EPSF);
  }
  f[IF_ERASE + w] = sigmoidf_(xi[325 + w]);
  f[IF_WVEC + w] = xi[389 + w];
  if (w < 4) {
    f[IF_RSTR + w] = oneplusf_(xi[256 + w]);
    f[IF_FREE + w] = sigmoidf_(xi[453 + w]);
    float a = xi[459 + w * 3], bb = xi[459 + w * 3 + 1], c = xi[459 + w * 3 + 2];
    float m = fmaxf(a, fmaxf(bb, c));
    float ea = expf(a - m), eb = expf(bb - m), ec = expf(c - m);
    float s = ea + eb + ec;
    f[IF_MODES + w * 3] = ea / s;
    f[IF_MODES + w * 3 + 1] = eb / s;
    f[IF_MODES + w * 3 + 2] = ec / s;
  }
  if (w == 0) {
    f[IF_WSTR] = oneplusf_(xi[324]);
    f[IF_AG] = sigmoidf_(xi[457]);
    f[IF_WG] = sigmoidf_(xi[458]);
  }
}

// 6) usage_new + allocation via log-space rank product (no sort, no barriers)
//    alloc_i = (1-u_i) * exp( sum_{j: u_j<u_i or (u_j==u_i && j<i)} ln u_j )
__global__ __launch_bounds__(256) void k_alloc(const float* __restrict__ rw,
                                               const float* __restrict__ usage,
                                               const float* __restrict__ wwp,
                                               float* __restrict__ ws,
                                               float* __restrict__ ousage) {
  __shared__ float2 ul[1024];
  const int q = blockIdx.x, b = blockIdx.y, t = threadIdx.x;
  const float* fr = ws + WS_IFACE + (size_t)b * IF_STRIDE + IF_FREE;
  const float f0 = fr[0], f1 = fr[1], f2 = fr[2], f3 = fr[3];
  #pragma unroll
  for (int c = 0; c < 4; ++c) {
    const int n = (c << 8) + t;
    const int i = (b << 10) + n;
    const float4 r4 = *(const float4*)(rw + (size_t)i * 4);
    float ret = (1.0f - f0 * r4.x) * (1.0f - f1 * r4.y) *
                (1.0f - f2 * r4.z) * (1.0f - f3 * r4.w);
    float u = usage[i], w = wwp[i];
    float un = (u + w - u * w) * ret;
    if (c == q) ousage[i] = un;
    ul[n] = make_float2(un, logf(un));
  }
  __syncthreads();
  const int i = (q << 8) + t;
  const float ui = ul[i].x;
  float s = 0.0f;
  #pragma unroll 4
  for (int j = 0; j < 1024; ++j) {
    float2 v = ul[j];
    bool sel = (v.x < ui) || (v.x == ui && j < i);
    s += sel ? v.y : 0.0f;
  }
  ws[WS_ALLOC + (b << 10) + i] = (1.0f - ui) * expf(s);
}

// 7) write-content softmax + ww + v-vectors + S/T + diag + memory_new (4 barriers)
__global__ __launch_bounds__(1024) void k_wcww(const float* __restrict__ mem,
                                               const float* __restrict__ rw,
                                               const float* __restrict__ prec,
                                               const float* __restrict__ link,
                                               float* __restrict__ ws,
                                               float* __restrict__ omem) {
  __shared__ float wkn[64];
  __shared__ float sh_ev[128];
  __shared__ float red[16];
  __shared__ float redST[144];
  const int b = blockIdx.x, t = threadIdx.x;
  const int wv = t >> 6, lane = t & 63;
  const float* f = ws + WS_IFACE + (size_t)b * IF_STRIDE;
  if (t < 64) wkn[t] = f[IF_WKN + t];
  else if (t < 128) sh_ev[t - 64] = f[IF_ERASE + (t - 64)];
  else if (t < 192) sh_ev[64 + (t - 128)] = f[IF_WVEC + (t - 128)];
  __syncthreads();
  const float* Mrow = mem + ((size_t)(b << 10) + t) * WDIM;
  float dot = 0.0f, ssq = 0.0f;
  #pragma unroll
  for (int w = 0; w < 64; w += 4) {
    float4 m4 = *(const float4*)(Mrow + w);
    float4 k4 = *(const float4*)(&wkn[w]);
    dot += m4.x * k4.x + m4.y * k4.y + m4.z * k4.z + m4.w * k4.w;
    ssq += m4.x * m4.x + m4.y * m4.y + m4.z * m4.z + m4.w * m4.w;
  }
  float sim = dot * rsqrtf(ssq + EPSF) * f[IF_WSTR];
  float m = sim;
  #pragma unroll
  for (int s = 32; s; s >>= 1) m = fmaxf(m, __shfl_xor(m, s));
  if (lane == 0) red[wv] = m;
  __syncthreads();
  float bmax = red[0];
  #pragma unroll
  for (int i = 1; i < 16; ++i) bmax = fmaxf(bmax, red[i]);
  float e = expf(sim - bmax);
  float se = e;
  #pragma unroll
  for (int s = 32; s; s >>= 1) se += __shfl_xor(se, s);
  if (lane == 0) redST[wv] = se;
  __syncthreads();
  float bsum = 0.0f;
  #pragma unroll
  for (int i = 0; i < 16; ++i) bsum += redST[i];
  float wc = e / bsum;
  float ag = f[IF_AG], wg = f[IF_WG];
  float ww = wg * (ag * ws[WS_ALLOC + (b << 10) + t] + (1.0f - ag) * wc);
  ws[WS_WW + (b << 10) + t] = ww;
  float4 r4 = *(const float4*)(rw + ((size_t)(b << 10) + t) * 4);
  float* vp = ws + WS_V + ((size_t)(b << 10) + t) * 8;
  float4 v0 = {r4.x, r4.y, r4.z, r4.w};
  float4 v1 = {ww * r4.x, ww * r4.y, ww * r4.z, ww * r4.w};
  *(float4*)vp = v0;
  *(float4*)(vp + 4) = v1;
  ws[WS_DIAG + (b << 10) + t] = link[((size_t)(b << 10) + t) * 1024 + t];
  float p = prec[(b << 10) + t];
  float vals[8] = {p * r4.x, p * r4.y, p * r4.z, p * r4.w,
                   ww * r4.x, ww * r4.y, ww * r4.z, ww * r4.w};
  #pragma unroll
  for (int k = 0; k < 8; ++k) {
    float v = vals[k];
    #pragma unroll
    for (int s = 32; s; s >>= 1) v += __shfl_xor(v, s);
    vals[k] = v;
  }
  if (lane == 0) {
    #pragma unroll
    for (int k = 0; k < 8; ++k) redST[16 + wv * 8 + k] = vals[k];
  }
  __syncthreads();
  if (t < 8) {
    float s = 0.0f;
    #pragma unroll
    for (int w = 0; w < 16; ++w) s += redST[16 + w * 8 + t];
    ws[WS_ST + b * 8 + t] = s;
  }
  float* Orow = omem + ((size_t)(b << 10) + t) * WDIM;
  #pragma unroll
  for (int w4 = 0; w4 < 16; ++w4) {
    float4 m4 = *(const float4*)(Mrow + (w4 << 2));
    float4 e4 = *(const float4*)(&sh_ev[w4 << 2]);
    float4 w4v = *(const float4*)(&sh_ev[64 + (w4 << 2)]);
    float4 o;
    o.x = m4.x * (1.0f - ww * e4.x) + ww * w4v.x;
    o.y = m4.y * (1.0f - ww * e4.y) + ww * w4v.y;
    o.z = m4.z * (1.0f - ww * e4.z) + ww * w4v.z;
    o.w = m4.w * (1.0f - ww * e4.w) + ww * w4v.w;
    *(float4*)(Orow + (w4 << 2)) = o;
  }
}

// 8) link pass v3: 512-thread blocks, global_load_lds staging (no staging VGPRs),
//    pre-swizzled global source -> linear LDS dest, one barrier per tile.
//    waves 0-3: row pass (rh=wv&1 row-half, jh=wv>>1 column-half of tile)
//    waves 4-7: col pass (row-quarter each), combine via scr, wave4 stores.
__global__ __launch_bounds__(512, 4) void k_link(const float* __restrict__ link,
                                                 float* __restrict__ ws) {
  __shared__ float buf[2][8192];   // [2][128][64]
  __shared__ float scr[2][1536];   // [2][3][8][64]
  const int rg = blockIdx.x;       // 0..7
  const int b = blockIdx.y;        // 0..63
  const int wv = threadIdx.x >> 6, lane = threadIdx.x & 63;
  const int i0 = rg << 7;
  const float* L = link + ((size_t)b << 20) + ((size_t)i0 << 10);
  const float* V = ws + WS_V + ((size_t)b << 13);

  // staging source pointers: 4 gload_lds per wave, each covers 4 rows x 64 cols
  const float* gsrc[4];
  {
    #pragma unroll
    for (int s = 0; s < 4; ++s) {
      const int q = (wv << 2) + s;
      const int row = (q << 2) + (lane >> 4);
      const int cb = (lane & 15) ^ (row & 15);
      gsrc[s] = L + (size_t)row * 1024 + (cb << 2);
    }
  }

  float rowAcc[8], colAcc[8], u[8], vvc[8], vvn[8];
  #pragma unroll
  for (int k = 0; k < 8; ++k) { rowAcc[k] = 0.0f; colAcc[k] = 0.0f; }

  const int rh = wv & 1, jh = wv >> 1;   // row waves
  const int rr = (rh << 6) + lane;
  const int iq = wv - 4;                 // col waves

  if (wv < 4) {
    const float* vp0 = V + (size_t)lane * 8;
    float4 a = *(const float4*)vp0, c = *(const float4*)(vp0 + 4);
    vvc[0]=a.x; vvc[1]=a.y; vvc[2]=a.z; vvc[3]=a.w;
    vvc[4]=c.x; vvc[5]=c.y; vvc[6]=c.z; vvc[7]=c.w;
  } else {
    const float* up = V + (size_t)(i0 + ((iq >> 1) << 6) + lane) * 8;
    float4 a = *(const float4*)up, c = *(const float4*)(up + 4);
    u[0]=a.x; u[1]=a.y; u[2]=a.z; u[3]=a.w;
    u[4]=c.x; u[5]=c.y; u[6]=c.z; u[7]=c.w;
  }

  // prologue: stage tile 0
  #pragma unroll
  for (int s = 0; s < 4; ++s) gl16(gsrc[s], &buf[0][((wv << 2) + s) << 8]);
  __syncthreads();

  int p = 0;
  #pragma unroll 1
  for (int jt = 0; jt < 16; ++jt) {
    if (jt < 15) {
      #pragma unroll
      for (int s = 0; s < 4; ++s)
        gl16(gsrc[s] + ((jt + 1) << 6), &buf[p ^ 1][((wv << 2) + s) << 8]);
    }
    if (wv < 4) {
      if (jt < 15) {
        const float* vp = V + (size_t)(((jt + 1) << 6) + lane) * 8;
        float4 a = *(const float4*)vp, c = *(const float4*)(vp + 4);
        vvn[0]=a.x; vvn[1]=a.y; vvn[2]=a.z; vvn[3]=a.w;
        vvn[4]=c.x; vvn[5]=c.y; vvn[6]=c.z; vvn[7]=c.w;
      }
      const float* base = &buf[p][rr << 6];
      const int rm = rr & 15;
      #pragma unroll
      for (int jb8 = 0; jb8 < 8; ++jb8) {
        const int jb = (jh << 3) + jb8;
        float4 f4 = *(const float4*)(base + ((jb ^ rm) << 2));
        #pragma unroll
        for (int q = 0; q < 4; ++q) {
          float fq = (q == 0) ? f4.x : (q == 1) ? f4.y : (q == 2) ? f4.z : f4.w;
          const int j = (jb << 2) + q;
          #pragma unroll
          for (int k = 0; k < 8; ++k)
            rowAcc[k] = fmaf(fq, readlane_f(vvc[k], j), rowAcc[k]);
        }
      }
    } else {
      #pragma unroll 8
      for (int ii = 0; ii < 32; ++ii) {
        const int i = (iq << 5) + ii;
        float fq = buf[p][(i << 6) + ((((lane >> 2) ^ (i & 15)) << 2) | (lane & 3))];
        #pragma unroll
        for (int k = 0; k < 8; ++k)
          colAcc[k] = fmaf(fq, readlane_f(u[k], i & 63), colAcc[k]);
      }
      if (wv >= 5) {
        #pragma unroll
        for (int k = 0; k < 8; ++k)
          scr[p][((wv - 5) << 9) + (k << 6) + lane] = colAcc[k];
      }
    }
    __syncthreads();   // drains gload_lds prefetch + makes scr visible
    if (wv == 4) {
      float* cp = ws + WS_COLPART + ((((size_t)rg << 6) + (size_t)b) << 13) +
                  (size_t)((jt << 6) + lane) * 8;
      float s[8];
      #pragma unroll
      for (int k = 0; k < 8; ++k)
        s[k] = colAcc[k] + scr[p][(0 << 9) + (k << 6) + lane] +
               scr[p][(1 << 9) + (k << 6) + lane] +
               scr[p][(2 << 9) + (k << 6) + lane];
      float4 c0 = {s[0], s[1], s[2], s[3]};
      float4 c1 = {s[4], s[5], s[6], s[7]};
      *(float4*)cp = c0;
      *(float4*)(cp + 4) = c1;
    }
    if (wv >= 4) {
      #pragma unroll
      for (int k = 0; k < 8; ++k) colAcc[k] = 0.0f;
    }
    if (wv < 4 && jt < 15) {
      #pragma unroll
      for (int k = 0; k < 8; ++k) vvc[k] = vvn[k];
    }
    p ^= 1;
  }

  // epilogue: combine row halves (wv0+wv2 -> rows 0..63, wv1+wv3 -> 64..127)
  if (wv == 2 || wv == 3) {
    #pragma unroll
    for (int k = 0; k < 8; ++k)
      buf[0][((wv & 1) << 9) + (lane << 3) + k] = rowAcc[k];
  }
  __syncthreads();
  if (wv < 2) {
    float* rp = ws + WS_ROWAB + ((size_t)(b << 10) + i0 + (wv << 6) + lane) * 8;
    #pragma unroll
    for (int k = 0; k < 8; ++k)
      rowAcc[k] += buf[0][(wv << 9) + (lane << 3) + k];
    float4 c0 = {rowAcc[0], rowAcc[1], rowAcc[2], rowAcc[3]};
    float4 c1 = {rowAcc[4], rowAcc[5], rowAcc[6], rowAcc[7]};
    *(float4*)rp = c0;
    *(float4*)(rp + 4) = c1;
  }
}

// 9) read-content softmax + fwd/bwd combine -> rw_new (3 barriers)
__global__ __launch_bounds__(1024) void k_final(const float* __restrict__ dout,
                                                const float* __restrict__ rw,
                                                const float* __restrict__ prec,
                                                const float* __restrict__ ws,
                                                float* __restrict__ orw) {
  __shared__ float kn[256];
  __shared__ float red4[64];
  __shared__ float red4b[64];
  const int b = blockIdx.x, t = threadIdx.x;
  const int wv = t >> 6, lane = t & 63;
  const float* f = ws + WS_IFACE + (size_t)b * IF_STRIDE;
  if (t < 256) kn[t] = f[IF_KN + t];
  __syncthreads();
  const float* Mrow = dout + O_MEM + ((size_t)(b << 10) + t) * WDIM;
  float dot0 = 0.f, dot1 = 0.f, dot2 = 0.f, dot3 = 0.f, ssq = 0.f;
  #pragma unroll
  for (int w = 0; w < 64; w += 4) {
    float4 m4 = *(const float4*)(Mrow + w);
    ssq += m4.x * m4.x + m4.y * m4.y + m4.z * m4.z + m4.w * m4.w;
    float4 k0 = *(const float4*)(&kn[w]);
    float4 k1 = *(const float4*)(&kn[64 + w]);
    float4 k2 = *(const float4*)(&kn[128 + w]);
    float4 k3 = *(const float4*)(&kn[192 + w]);
    dot0 += m4.x * k0.x + m4.y * k0.y + m4.z * k0.z + m4.w * k0.w;
    dot1 += m4.x * k1.x + m4.y * k1.y + m4.z * k1.z + m4.w * k1.w;
    dot2 += m4.x * k2.x + m4.y * k2.y + m4.z * k2.z + m4.w * k2.w;
    dot3 += m4.x * k3.x + m4.y * k3.y + m4.z * k3.z + m4.w * k3.w;
  }
  float rs = rsqrtf(ssq + EPSF);
  float sim[4] = {dot0 * rs * f[IF_RSTR + 0], dot1 * rs * f[IF_RSTR + 1],
                  dot2 * rs * f[IF_RSTR + 2], dot3 * rs * f[IF_RSTR + 3]};
  float mx[4];
  #pragma unroll
  for (int r = 0; r < 4; ++r) {
    float m = sim[r];
    #pragma unroll
    for (int s = 32; s; s >>= 1) m = fmaxf(m, __shfl_xor(m, s));
    mx[r] = m;
  }
  if (lane == 0) {
    #pragma unroll
    for (int r = 0; r < 4; ++r) red4[wv * 4 + r] = mx[r];
  }
  __syncthreads();
  float e[4], ssum[4];
  #pragma unroll
  for (int r = 0; r < 4; ++r) {
    float m = red4[r];
    #pragma unroll
    for (int i = 1; i < 16; ++i) m = fmaxf(m, red4[i * 4 + r]);
    e[r] = expf(sim[r] - m);
    float se = e[r];
    #pragma unroll
    for (int s = 32; s; s >>= 1) se += __shfl_xor(se, s);
    ssum[r] = se;
  }
  if (lane == 0) {
    #pragma unroll
    for (int r = 0; r < 4; ++r) red4b[wv * 4 + r] = ssum[r];
  }
  __syncthreads();
  float cr[4];
  #pragma unroll
  for (int r = 0; r < 4; ++r) {
    float s = 0.0f;
    #pragma unroll
    for (int i = 0; i < 16; ++i) s += red4b[i * 4 + r];
    cr[r] = e[r] / s;
  }
  const size_t bn = (size_t)(b << 10) + t;
  float ca[8];
  #pragma unroll
  for (int k = 0; k < 8; ++k) ca[k] = 0.0f;
  #pragma unroll
  for (int rg = 0; rg < 8; ++rg) {
    const float* p = ws + WS_COLPART + ((((size_t)rg << 6) + (size_t)b) << 13) +
                     (size_t)t * 8;
    float4 a = *(const float4*)p;
    float4 c2 = *(const float4*)(p + 4);
    ca[0] += a.x; ca[1] += a.y; ca[2] += a.z; ca[3] += a.w;
    ca[4] += c2.x; ca[5] += c2.y; ca[6] += c2.z; ca[7] += c2.w;
  }
  const float* ra = ws + WS_ROWAB + bn * 8;
  float d = ws[WS_DIAG + bn];
  float w_ = ws[WS_WW + bn];
  float pn = prec[bn];
  float4 r4 = *(const float4*)(rw + bn * 4);
  float rv[4] = {r4.x, r4.y, r4.z, r4.w};
  const float* ST = ws + WS_ST + b * 8;
  float ow = 1.0f - w_;
  float res[4];
  #pragma unroll
  for (int r = 0; r < 4; ++r) {
    float A = ra[r], Ap = ra[4 + r], Bv = ca[r], Bp = ca[4 + r];
    float fwd = ow * (A - d * rv[r]) - (Ap - w_ * d * rv[r]) + w_ * (ST[r] - pn * rv[r]);
    float bwd = ow * (Bv - d * rv[r]) - (Bp - w_ * d * rv[r]) + pn * (ST[4 + r] - w_ * rv[r]);
    res[r] = f[IF_MODES + r * 3] * bwd + f[IF_MODES + r * 3 + 1] * cr[r] +
             f[IF_MODES + r * 3 + 2] * fwd;
  }
  float4 o = {res[0], res[1], res[2], res[3]};
  *(float4*)(orw + bn * 4) = o;
}

extern "C" void kernel_launch(void* const* d_in, const int* in_sizes, int n_in,
                              void* d_out, int out_size, void* d_ws, size_t ws_size,
                              hipStream_t stream) {
  const float* x     = (const float*)d_in[0];
  const float* rw    = (const float*)d_in[1];
  const float* mem   = (const float*)d_in[2];
  const float* usage = (const float*)d_in[3];
  const float* wwp   = (const float*)d_in[4];
  const float* link  = (const float*)d_in[5];
  const float* prec  = (const float*)d_in[6];
  const float* W1    = (const float*)d_in[7];
  const float* b1    = (const float*)d_in[8];
  const float* Wo    = (const float*)d_in[9];
  const float* bo    = (const float*)d_in[10];
  const float* Wr    = (const float*)d_in[11];
  const float* br    = (const float*)d_in[12];
  const float* Wxi   = (const float*)d_in[13];
  const float* bxi   = (const float*)d_in[14];
  float* out = (float*)d_out;
  float* ws = (float*)d_ws;

  k_read_flat<<<dim3(4, 64), 1024, 0, stream>>>(mem, rw, ws);
  k_h<<<dim3(2, 64), 256, 0, stream>>>(x, W1, b1, ws);
  k_out<<<64, 256, 0, stream>>>(Wo, bo, Wr, br, ws, out);
  k_xi<<<dim3(2, 64), 256, 0, stream>>>(Wxi, bxi, ws, out);
  k_iface<<<64, 64, 0, stream>>>(out, ws);
  k_alloc<<<dim3(4, 64), 256, 0, stream>>>(rw, usage, wwp, ws, out + O_USAGE);
  k_wcww<<<64, 1024, 0, stream>>>(mem, rw, prec, link, ws, out + O_MEM);
  k_link<<<dim3(8, 64), 512, 0, stream>>>(link, ws);
  k_final<<<64, 1024, 0, stream>>>(out, rw, prec, ws, out + O_RW);
}

// Round 6
// 331.101 us; speedup vs baseline: 1.6596x; 1.0888x over previous
//
#include <hip/hip_runtime.h>

#define NB 64
#define NN 1024
#define WDIM 64
#define RR 4
#define HID 512
#define XID 471
#define EPSF 1e-6f

// ---- d_out offsets (floats) ----
#define O_OUT   0
#define O_XI    16384
#define O_RW    46528
#define O_MEM   308672
#define O_USAGE 4502976

// ---- ws offsets (floats) ----
#define WS_RFPART   0          // [4][64][256] read_flat partials
#define WS_H        65536      // [64][512]
#define WS_IFACE    98304      // [64][480]
#define WS_ALLOC    129024     // [64][1024]
#define WS_WW       194560     // [64][1024]
#define WS_V        260096     // [64][1024][8]
#define WS_DIAG     784896     // [64][1024]
#define WS_ROWAB    850432     // [64][1024][8]
#define WS_COLPART  1899008    // [8][64][1024][8] col partials (16.8 MB)
#define WS_EW       6093312    // [4][64] write-softmax partial sums
#define WS_SIMWE    6093568    // [64][1024] exp(sim_w)
#define WS_ERP      6159104    // [4][64][4] read-softmax partial sums
#define WS_ER       6160128    // [64][1024][4] exp(sim_r)
#define WS_STP      6422272    // [4][64][8] ST partials

// ---- iface per-b layout (stride 480) ----
#define IF_KN     0
#define IF_WKN    256
#define IF_ERASE  320
#define IF_WVEC   384
#define IF_RSTR   448
#define IF_FREE   452
#define IF_WSTR   456
#define IF_AG     457
#define IF_WG     458
#define IF_MODES  460
#define IF_STRIDE 480

__device__ __forceinline__ float sigmoidf_(float x) { return 1.0f / (1.0f + expf(-x)); }
__device__ __forceinline__ float oneplusf_(float x) {
  return 1.0f + ((x > 20.0f) ? x : log1pf(expf(x)));
}
__device__ __forceinline__ float readlane_f(float v, int l) {
  return __int_as_float(__builtin_amdgcn_readlane(__float_as_int(v), l));
}

typedef const __attribute__((address_space(1))) void gas_void;
typedef __attribute__((address_space(3))) void las_void;
__device__ __forceinline__ void gl16(const float* g, float* l) {
  __builtin_amdgcn_global_load_lds((gas_void*)g, (las_void*)l, 16, 0, 0);
}

// 1) read_flat partials
__global__ __launch_bounds__(1024) void k_read_flat(const float* __restrict__ mem,
                                                    const float* __restrict__ rw,
                                                    float* __restrict__ ws) {
  __shared__ float red[1024];
  const int q = blockIdx.x, b = blockIdx.y, t = threadIdx.x;
  const int rwi = t & 255;
  const int r = rwi >> 6, w = rwi & 63;
  const int ng = t >> 8;
  const int n0 = (q << 8) + (ng << 6);
  const float* M  = mem + ((size_t)(b << 10) + n0) * WDIM;
  const float* Rw = rw  + ((size_t)(b << 10) + n0) * RR;
  float a0 = 0.f, a1 = 0.f, a2 = 0.f, a3 = 0.f;
  for (int n = 0; n < 64; n += 4) {
    a0 += M[(n + 0) * WDIM + w] * Rw[(n + 0) * RR + r];
    a1 += M[(n + 1) * WDIM + w] * Rw[(n + 1) * RR + r];
    a2 += M[(n + 2) * WDIM + w] * Rw[(n + 2) * RR + r];
    a3 += M[(n + 3) * WDIM + w] * Rw[(n + 3) * RR + r];
  }
  red[t] = (a0 + a1) + (a2 + a3);
  __syncthreads();
  if (t < 256)
    ws[WS_RFPART + (((q << 6) + b) << 8) + t] =
        red[t] + red[t + 256] + red[t + 512] + red[t + 768];
}

// 2) h = relu([x, read_flat] @ W1 + b1), col-split grid (2,64)
__global__ __launch_bounds__(256) void k_h(const float* __restrict__ x,
                                           const float* __restrict__ W1,
                                           const float* __restrict__ b1,
                                           float* __restrict__ ws) {
  __shared__ float cat[768];
  const int ch = blockIdx.x, b = blockIdx.y, t = threadIdx.x;
  cat[t] = x[b * 512 + t];
  cat[256 + t] = x[b * 512 + 256 + t];
  {
    float s = 0.0f;
    #pragma unroll
    for (int q = 0; q < 4; ++q) s += ws[WS_RFPART + (((q << 6) + b) << 8) + t];
    cat[512 + t] = s;
  }
  __syncthreads();
  const int col = (ch << 8) + t;
  float acc = b1[col];
  #pragma unroll 4
  for (int k = 0; k < 768; ++k) acc += cat[k] * W1[k * 512 + col];
  ws[WS_H + b * 512 + col] = fmaxf(acc, 0.0f);
}

// 3) output = h@Wo + bo + read_flat@Wr + br
__global__ __launch_bounds__(256) void k_out(const float* __restrict__ Wo,
                                             const float* __restrict__ bo,
                                             const float* __restrict__ Wr,
                                             const float* __restrict__ br,
                                             const float* __restrict__ ws,
                                             float* __restrict__ out) {
  __shared__ float h[512];
  __shared__ float rf[256];
  const int b = blockIdx.x, t = threadIdx.x;
  h[t] = ws[WS_H + b * 512 + t];
  h[256 + t] = ws[WS_H + b * 512 + 256 + t];
  {
    float s = 0.0f;
    #pragma unroll
    for (int q = 0; q < 4; ++q) s += ws[WS_RFPART + (((q << 6) + b) << 8) + t];
    rf[t] = s;
  }
  __syncthreads();
  float acc = bo[t] + br[t];
  #pragma unroll 4
  for (int j = 0; j < 512; ++j) acc += h[j] * Wo[j * 256 + t];
  #pragma unroll 4
  for (int j = 0; j < 256; ++j) acc += rf[j] * Wr[j * 256 + t];
  out[O_OUT + b * 256 + t] = acc;
}

// 4) xi = h@Wxi + bxi, col-split grid (2,64)
__global__ __launch_bounds__(256) void k_xi(const float* __restrict__ Wxi,
                                            const float* __restrict__ bxi,
                                            const float* __restrict__ ws,
                                            float* __restrict__ out) {
  __shared__ float h[512];
  const int ch = blockIdx.x, b = blockIdx.y, t = threadIdx.x;
  h[t] = ws[WS_H + b * 512 + t];
  h[256 + t] = ws[WS_H + b * 512 + 256 + t];
  __syncthreads();
  const int col = (ch << 8) + t;
  if (col < XID) {
    float acc = bxi[col];
    #pragma unroll 4
    for (int j = 0; j < 512; ++j) acc += h[j] * Wxi[j * XID + col];
    out[O_XI + b * XID + col] = acc;
  }
}

// 5) interface activations (one wave per b)
__global__ __launch_bounds__(64) void k_iface(const float* __restrict__ out,
                                              float* __restrict__ ws) {
  const int b = blockIdx.x, w = threadIdx.x;
  const float* xi = out + O_XI + b * XID;
  float* f = ws + WS_IFACE + (size_t)b * IF_STRIDE;
  #pragma unroll
  for (int r = 0; r < 4; ++r) {
    float kv = xi[r * 64 + w];
    float ss = kv * kv;
    #pragma unroll
    for (int s = 32; s; s >>= 1) ss += __shfl_xor(ss, s);
    f[IF_KN + r * 64 + w] = kv * rsqrtf(ss + EPSF);
  }
  {
    float kv = xi[260 + w];
    float ss = kv * kv;
    #pragma unroll
    for (int s = 32; s; s >>= 1) ss += __shfl_xor(ss, s);
    f[IF_WKN + w] = kv * rsqrtf(ss + EPSF);
  }
  f[IF_ERASE + w] = sigmoidf_(xi[325 + w]);
  f[IF_WVEC + w] = xi[389 + w];
  if (w < 4) {
    f[IF_RSTR + w] = oneplusf_(xi[256 + w]);
    f[IF_FREE + w] = sigmoidf_(xi[453 + w]);
    float a = xi[459 + w * 3], bb = xi[459 + w * 3 + 1], c = xi[459 + w * 3 + 2];
    float m = fmaxf(a, fmaxf(bb, c));
    float ea = expf(a - m), eb = expf(bb - m), ec = expf(c - m);
    float s = ea + eb + ec;
    f[IF_MODES + w * 3] = ea / s;
    f[IF_MODES + w * 3 + 1] = eb / s;
    f[IF_MODES + w * 3 + 2] = ec / s;
  }
  if (w == 0) {
    f[IF_WSTR] = oneplusf_(xi[324]);
    f[IF_AG] = sigmoidf_(xi[457]);
    f[IF_WG] = sigmoidf_(xi[458]);
  }
}

// 6) usage_new + allocation via log-space rank product
__global__ __launch_bounds__(256) void k_alloc(const float* __restrict__ rw,
                                               const float* __restrict__ usage,
                                               const float* __restrict__ wwp,
                                               float* __restrict__ ws,
                                               float* __restrict__ ousage) {
  __shared__ float2 ul[1024];
  const int q = blockIdx.x, b = blockIdx.y, t = threadIdx.x;
  const float* fr = ws + WS_IFACE + (size_t)b * IF_STRIDE + IF_FREE;
  const float f0 = fr[0], f1 = fr[1], f2 = fr[2], f3 = fr[3];
  #pragma unroll
  for (int c = 0; c < 4; ++c) {
    const int n = (c << 8) + t;
    const int i = (b << 10) + n;
    const float4 r4 = *(const float4*)(rw + (size_t)i * 4);
    float ret = (1.0f - f0 * r4.x) * (1.0f - f1 * r4.y) *
                (1.0f - f2 * r4.z) * (1.0f - f3 * r4.w);
    float u = usage[i], w = wwp[i];
    float un = (u + w - u * w) * ret;
    if (c == q) ousage[i] = un;
    ul[n] = make_float2(un, logf(un));
  }
  __syncthreads();
  const int i = (q << 8) + t;
  const float ui = ul[i].x;
  float s = 0.0f;
  #pragma unroll 4
  for (int j = 0; j < 1024; ++j) {
    float2 v = ul[j];
    bool sel = (v.x < ui) || (v.x == ui && j < i);
    s += sel ? v.y : 0.0f;
  }
  ws[WS_ALLOC + (b << 10) + i] = (1.0f - ui) * expf(s);
}

// 7a) write-content: e = exp(sim_w) (no max-sub; |sim|<~3), partial sums, diag
__global__ __launch_bounds__(256) void k_wcww_a(const float* __restrict__ mem,
                                                const float* __restrict__ link,
                                                float* __restrict__ ws) {
  __shared__ float wkn[64];
  __shared__ float red[4];
  const int q = blockIdx.x, b = blockIdx.y, t = threadIdx.x;
  const int wv = t >> 6, lane = t & 63;
  const float* f = ws + WS_IFACE + (size_t)b * IF_STRIDE;
  if (t < 64) wkn[t] = f[IF_WKN + t];
  __syncthreads();
  const int n = (q << 8) + t;
  const size_t bn = (size_t)(b << 10) + n;
  const float* Mrow = mem + bn * WDIM;
  float dot = 0.0f, ssq = 0.0f;
  #pragma unroll
  for (int w = 0; w < 64; w += 4) {
    float4 m4 = *(const float4*)(Mrow + w);
    float4 k4 = *(const float4*)(&wkn[w]);
    dot += m4.x * k4.x + m4.y * k4.y + m4.z * k4.z + m4.w * k4.w;
    ssq += m4.x * m4.x + m4.y * m4.y + m4.z * m4.z + m4.w * m4.w;
  }
  float e = expf(dot * rsqrtf(ssq + EPSF) * f[IF_WSTR]);
  ws[WS_SIMWE + bn] = e;
  ws[WS_DIAG + bn] = link[bn * 1024 + n];
  float se = e;
  #pragma unroll
  for (int s = 32; s; s >>= 1) se += __shfl_xor(se, s);
  if (lane == 0) red[wv] = se;
  __syncthreads();
  if (t == 0) ws[WS_EW + (q << 6) + b] = red[0] + red[1] + red[2] + red[3];
}

// 7b) ww + V + ST partials + memory_new + fused read-content exp + partials
__global__ __launch_bounds__(256) void k_wcww_b(const float* __restrict__ mem,
                                                const float* __restrict__ rw,
                                                const float* __restrict__ prec,
                                                float* __restrict__ ws,
                                                float* __restrict__ omem) {
  __shared__ float kn[256];
  __shared__ float shev[128];
  __shared__ float red8[4][8];
  __shared__ float red4[4][4];
  const int q = blockIdx.x, b = blockIdx.y, t = threadIdx.x;
  const int wv = t >> 6, lane = t & 63;
  const float* f = ws + WS_IFACE + (size_t)b * IF_STRIDE;
  kn[t] = f[IF_KN + t];
  if (t < 64) shev[t] = f[IF_ERASE + t];
  else if (t < 128) shev[t] = f[IF_WVEC + (t - 64)];
  __syncthreads();
  const float denom = ws[WS_EW + b] + ws[WS_EW + 64 + b] +
                      ws[WS_EW + 128 + b] + ws[WS_EW + 192 + b];
  const int n = (q << 8) + t;
  const size_t bn = (size_t)(b << 10) + n;
  float wc = ws[WS_SIMWE + bn] / denom;
  float ag = f[IF_AG], wg = f[IF_WG];
  float ww = wg * (ag * ws[WS_ALLOC + bn] + (1.0f - ag) * wc);
  ws[WS_WW + bn] = ww;
  float4 r4 = *(const float4*)(rw + bn * 4);
  float* vp = ws + WS_V + bn * 8;
  float4 v0 = {r4.x, r4.y, r4.z, r4.w};
  float4 v1 = {ww * r4.x, ww * r4.y, ww * r4.z, ww * r4.w};
  *(float4*)vp = v0;
  *(float4*)(vp + 4) = v1;
  // ST partials
  float p = prec[bn];
  float vals[8] = {p * r4.x, p * r4.y, p * r4.z, p * r4.w,
                   ww * r4.x, ww * r4.y, ww * r4.z, ww * r4.w};
  #pragma unroll
  for (int k = 0; k < 8; ++k) {
    float v = vals[k];
    #pragma unroll
    for (int s = 32; s; s >>= 1) v += __shfl_xor(v, s);
    vals[k] = v;
  }
  if (lane == 0) {
    #pragma unroll
    for (int k = 0; k < 8; ++k) red8[wv][k] = vals[k];
  }
  // memory_new + read-content dot (memory_new row in regs)
  const float* Mrow = mem + bn * WDIM;
  float* Orow = omem + bn * WDIM;
  float dr0 = 0.f, dr1 = 0.f, dr2 = 0.f, dr3 = 0.f, ssqn = 0.f;
  #pragma unroll
  for (int w4 = 0; w4 < 16; ++w4) {
    float4 m4 = *(const float4*)(Mrow + (w4 << 2));
    float4 e4 = *(const float4*)(&shev[w4 << 2]);
    float4 wv4 = *(const float4*)(&shev[64 + (w4 << 2)]);
    float4 o;
    o.x = m4.x * (1.0f - ww * e4.x) + ww * wv4.x;
    o.y = m4.y * (1.0f - ww * e4.y) + ww * wv4.y;
    o.z = m4.z * (1.0f - ww * e4.z) + ww * wv4.z;
    o.w = m4.w * (1.0f - ww * e4.w) + ww * wv4.w;
    *(float4*)(Orow + (w4 << 2)) = o;
    ssqn += o.x * o.x + o.y * o.y + o.z * o.z + o.w * o.w;
    float4 k0 = *(const float4*)(&kn[w4 << 2]);
    float4 k1 = *(const float4*)(&kn[64 + (w4 << 2)]);
    float4 k2 = *(const float4*)(&kn[128 + (w4 << 2)]);
    float4 k3 = *(const float4*)(&kn[192 + (w4 << 2)]);
    dr0 += o.x * k0.x + o.y * k0.y + o.z * k0.z + o.w * k0.w;
    dr1 += o.x * k1.x + o.y * k1.y + o.z * k1.z + o.w * k1.w;
    dr2 += o.x * k2.x + o.y * k2.y + o.z * k2.z + o.w * k2.w;
    dr3 += o.x * k3.x + o.y * k3.y + o.z * k3.z + o.w * k3.w;
  }
  float rs = rsqrtf(ssqn + EPSF);
  float er[4] = {expf(dr0 * rs * f[IF_RSTR + 0]), expf(dr1 * rs * f[IF_RSTR + 1]),
                 expf(dr2 * rs * f[IF_RSTR + 2]), expf(dr3 * rs * f[IF_RSTR + 3])};
  float4 er4 = {er[0], er[1], er[2], er[3]};
  *(float4*)(ws + WS_ER + bn * 4) = er4;
  #pragma unroll
  for (int r = 0; r < 4; ++r) {
    float v = er[r];
    #pragma unroll
    for (int s = 32; s; s >>= 1) v += __shfl_xor(v, s);
    er[r] = v;
  }
  if (lane == 0) {
    #pragma unroll
    for (int r = 0; r < 4; ++r) red4[wv][r] = er[r];
  }
  __syncthreads();
  if (t < 8)
    ws[WS_STP + (((q << 6) + b) << 3) + t] =
        red8[0][t] + red8[1][t] + red8[2][t] + red8[3][t];
  else if (t >= 64 && t < 68)
    ws[WS_ERP + (((q << 6) + b) << 2) + (t - 64)] =
        red4[0][t - 64] + red4[1][t - 64] + red4[2][t - 64] + red4[3][t - 64];
}

// 8) link pass (unchanged from r5)
__global__ __launch_bounds__(512, 4) void k_link(const float* __restrict__ link,
                                                 float* __restrict__ ws) {
  __shared__ float buf[2][8192];   // [2][128][64]
  __shared__ float scr[2][1536];   // [2][3][8][64]
  const int rg = blockIdx.x;       // 0..7
  const int b = blockIdx.y;        // 0..63
  const int wv = threadIdx.x >> 6, lane = threadIdx.x & 63;
  const int i0 = rg << 7;
  const float* L = link + ((size_t)b << 20) + ((size_t)i0 << 10);
  const float* V = ws + WS_V + ((size_t)b << 13);

  const float* gsrc[4];
  {
    #pragma unroll
    for (int s = 0; s < 4; ++s) {
      const int q = (wv << 2) + s;
      const int row = (q << 2) + (lane >> 4);
      const int cb = (lane & 15) ^ (row & 15);
      gsrc[s] = L + (size_t)row * 1024 + (cb << 2);
    }
  }

  float rowAcc[8], colAcc[8], u[8], vvc[8], vvn[8];
  #pragma unroll
  for (int k = 0; k < 8; ++k) { rowAcc[k] = 0.0f; colAcc[k] = 0.0f; }

  const int rh = wv & 1, jh = wv >> 1;
  const int rr = (rh << 6) + lane;
  const int iq = wv - 4;

  if (wv < 4) {
    const float* vp0 = V + (size_t)lane * 8;
    float4 a = *(const float4*)vp0, c = *(const float4*)(vp0 + 4);
    vvc[0]=a.x; vvc[1]=a.y; vvc[2]=a.z; vvc[3]=a.w;
    vvc[4]=c.x; vvc[5]=c.y; vvc[6]=c.z; vvc[7]=c.w;
  } else {
    const float* up = V + (size_t)(i0 + ((iq >> 1) << 6) + lane) * 8;
    float4 a = *(const float4*)up, c = *(const float4*)(up + 4);
    u[0]=a.x; u[1]=a.y; u[2]=a.z; u[3]=a.w;
    u[4]=c.x; u[5]=c.y; u[6]=c.z; u[7]=c.w;
  }

  #pragma unroll
  for (int s = 0; s < 4; ++s) gl16(gsrc[s], &buf[0][((wv << 2) + s) << 8]);
  __syncthreads();

  int p = 0;
  #pragma unroll 1
  for (int jt = 0; jt < 16; ++jt) {
    if (jt < 15) {
      #pragma unroll
      for (int s = 0; s < 4; ++s)
        gl16(gsrc[s] + ((jt + 1) << 6), &buf[p ^ 1][((wv << 2) + s) << 8]);
    }
    if (wv < 4) {
      if (jt < 15) {
        const float* vp = V + (size_t)(((jt + 1) << 6) + lane) * 8;
        float4 a = *(const float4*)vp, c = *(const float4*)(vp + 4);
        vvn[0]=a.x; vvn[1]=a.y; vvn[2]=a.z; vvn[3]=a.w;
        vvn[4]=c.x; vvn[5]=c.y; vvn[6]=c.z; vvn[7]=c.w;
      }
      const float* base = &buf[p][rr << 6];
      const int rm = rr & 15;
      #pragma unroll
      for (int jb8 = 0; jb8 < 8; ++jb8) {
        const int jb = (jh << 3) + jb8;
        float4 f4 = *(const float4*)(base + ((jb ^ rm) << 2));
        #pragma unroll
        for (int q = 0; q < 4; ++q) {
          float fq = (q == 0) ? f4.x : (q == 1) ? f4.y : (q == 2) ? f4.z : f4.w;
          const int j = (jb << 2) + q;
          #pragma unroll
          for (int k = 0; k < 8; ++k)
            rowAcc[k] = fmaf(fq, readlane_f(vvc[k], j), rowAcc[k]);
        }
      }
    } else {
      #pragma unroll 8
      for (int ii = 0; ii < 32; ++ii) {
        const int i = (iq << 5) + ii;
        float fq = buf[p][(i << 6) + ((((lane >> 2) ^ (i & 15)) << 2) | (lane & 3))];
        #pragma unroll
        for (int k = 0; k < 8; ++k)
          colAcc[k] = fmaf(fq, readlane_f(u[k], i & 63), colAcc[k]);
      }
      if (wv >= 5) {
        #pragma unroll
        for (int k = 0; k < 8; ++k)
          scr[p][((wv - 5) << 9) + (k << 6) + lane] = colAcc[k];
      }
    }
    __syncthreads();
    if (wv == 4) {
      float* cp = ws + WS_COLPART + ((((size_t)rg << 6) + (size_t)b) << 13) +
                  (size_t)((jt << 6) + lane) * 8;
      float s[8];
      #pragma unroll
      for (int k = 0; k < 8; ++k)
        s[k] = colAcc[k] + scr[p][(0 << 9) + (k << 6) + lane] +
               scr[p][(1 << 9) + (k << 6) + lane] +
               scr[p][(2 << 9) + (k << 6) + lane];
      float4 c0 = {s[0], s[1], s[2], s[3]};
      float4 c1 = {s[4], s[5], s[6], s[7]};
      *(float4*)cp = c0;
      *(float4*)(cp + 4) = c1;
    }
    if (wv >= 4) {
      #pragma unroll
      for (int k = 0; k < 8; ++k) colAcc[k] = 0.0f;
    }
    if (wv < 4 && jt < 15) {
      #pragma unroll
      for (int k = 0; k < 8; ++k) vvc[k] = vvn[k];
    }
    p ^= 1;
  }

  if (wv == 2 || wv == 3) {
    #pragma unroll
    for (int k = 0; k < 8; ++k)
      buf[0][((wv & 1) << 9) + (lane << 3) + k] = rowAcc[k];
  }
  __syncthreads();
  if (wv < 2) {
    float* rp = ws + WS_ROWAB + ((size_t)(b << 10) + i0 + (wv << 6) + lane) * 8;
    #pragma unroll
    for (int k = 0; k < 8; ++k)
      rowAcc[k] += buf[0][(wv << 9) + (lane << 3) + k];
    float4 c0 = {rowAcc[0], rowAcc[1], rowAcc[2], rowAcc[3]};
    float4 c1 = {rowAcc[4], rowAcc[5], rowAcc[6], rowAcc[7]};
    *(float4*)rp = c0;
    *(float4*)(rp + 4) = c1;
  }
}

// 9) final combine: grid (4,64), no barriers
__global__ __launch_bounds__(256) void k_final(const float* __restrict__ rw,
                                               const float* __restrict__ prec,
                                               const float* __restrict__ ws,
                                               float* __restrict__ orw) {
  const int q = blockIdx.x, b = blockIdx.y, t = threadIdx.x;
  const float* f = ws + WS_IFACE + (size_t)b * IF_STRIDE;
  float denom[4], ST[8];
  #pragma unroll
  for (int r = 0; r < 4; ++r)
    denom[r] = ws[WS_ERP + (b << 2) + r] + ws[WS_ERP + ((64 + b) << 2) + r] +
               ws[WS_ERP + ((128 + b) << 2) + r] + ws[WS_ERP + ((192 + b) << 2) + r];
  #pragma unroll
  for (int k = 0; k < 8; ++k)
    ST[k] = ws[WS_STP + (b << 3) + k] + ws[WS_STP + ((64 + b) << 3) + k] +
            ws[WS_STP + ((128 + b) << 3) + k] + ws[WS_STP + ((192 + b) << 3) + k];
  const int n = (q << 8) + t;
  const size_t bn = (size_t)(b << 10) + n;
  float4 er4 = *(const float4*)(ws + WS_ER + bn * 4);
  float cr[4] = {er4.x / denom[0], er4.y / denom[1], er4.z / denom[2], er4.w / denom[3]};
  float ca[8];
  #pragma unroll
  for (int k = 0; k < 8; ++k) ca[k] = 0.0f;
  #pragma unroll
  for (int rg = 0; rg < 8; ++rg) {
    const float* p = ws + WS_COLPART + ((((size_t)rg << 6) + (size_t)b) << 13) +
                     (size_t)n * 8;
    float4 a = *(const float4*)p;
    float4 c2 = *(const float4*)(p + 4);
    ca[0] += a.x; ca[1] += a.y; ca[2] += a.z; ca[3] += a.w;
    ca[4] += c2.x; ca[5] += c2.y; ca[6] += c2.z; ca[7] += c2.w;
  }
  const float* ra = ws + WS_ROWAB + bn * 8;
  float d = ws[WS_DIAG + bn];
  float w_ = ws[WS_WW + bn];
  float pn = prec[bn];
  float4 r4 = *(const float4*)(rw + bn * 4);
  float rv[4] = {r4.x, r4.y, r4.z, r4.w};
  float ow = 1.0f - w_;
  float res[4];
  #pragma unroll
  for (int r = 0; r < 4; ++r) {
    float A = ra[r], Ap = ra[4 + r], Bv = ca[r], Bp = ca[4 + r];
    float fwd = ow * (A - d * rv[r]) - (Ap - w_ * d * rv[r]) + w_ * (ST[r] - pn * rv[r]);
    float bwd = ow * (Bv - d * rv[r]) - (Bp - w_ * d * rv[r]) + pn * (ST[4 + r] - w_ * rv[r]);
    res[r] = f[IF_MODES + r * 3] * bwd + f[IF_MODES + r * 3 + 1] * cr[r] +
             f[IF_MODES + r * 3 + 2] * fwd;
  }
  float4 o = {res[0], res[1], res[2], res[3]};
  *(float4*)(orw + bn * 4) = o;
}

extern "C" void kernel_launch(void* const* d_in, const int* in_sizes, int n_in,
                              void* d_out, int out_size, void* d_ws, size_t ws_size,
                              hipStream_t stream) {
  const float* x     = (const float*)d_in[0];
  const float* rw    = (const float*)d_in[1];
  const float* mem   = (const float*)d_in[2];
  const float* usage = (const float*)d_in[3];
  const float* wwp   = (const float*)d_in[4];
  const float* link  = (const float*)d_in[5];
  const float* prec  = (const float*)d_in[6];
  const float* W1    = (const float*)d_in[7];
  const float* b1    = (const float*)d_in[8];
  const float* Wo    = (const float*)d_in[9];
  const float* bo    = (const float*)d_in[10];
  const float* Wr    = (const float*)d_in[11];
  const float* br    = (const float*)d_in[12];
  const float* Wxi   = (const float*)d_in[13];
  const float* bxi   = (const float*)d_in[14];
  float* out = (float*)d_out;
  float* ws = (float*)d_ws;

  k_read_flat<<<dim3(4, 64), 1024, 0, stream>>>(mem, rw, ws);
  k_h<<<dim3(2, 64), 256, 0, stream>>>(x, W1, b1, ws);
  k_xi<<<dim3(2, 64), 256, 0, stream>>>(Wxi, bxi, ws, out);
  k_iface<<<64, 64, 0, stream>>>(out, ws);
  k_out<<<64, 256, 0, stream>>>(Wo, bo, Wr, br, ws, out);
  k_alloc<<<dim3(4, 64), 256, 0, stream>>>(rw, usage, wwp, ws, out + O_USAGE);
  k_wcww_a<<<dim3(4, 64), 256, 0, stream>>>(mem, link, ws);
  k_wcww_b<<<dim3(4, 64), 256, 0, stream>>>(mem, rw, prec, ws, out + O_MEM);
  k_link<<<dim3(8, 64), 512, 0, stream>>>(link, ws);
  k_final<<<dim3(4, 64), 256, 0, stream>>>(rw, prec, ws, out + O_RW);
}